// Round 4
// baseline (654.009 us; speedup 1.0000x reference)
//
#include <hip/hip_runtime.h>
#include <hip/hip_bf16.h>

#define BN 8
#define HN 128
#define WN 128
#define CN 256
#define DTC 0.2f
#define EPSV 1e-3f
#define NTH 1024

#define SW 138     // s0s w-stride (floats): 552 B/row, 8B-aligned rows; 4-ch group stride 552 dw ≡ 8 mod 32 -> 2-way (free) staged writes
#define HBS 132    // h-buffer row stride (floats): ≡ 4 mod 32 banks -> de-conflicts output column reads

// ---- dtype-generic helpers (compute stays f32) ----
__device__ __forceinline__ float ldf(const float* p)            { return *p; }
__device__ __forceinline__ float ldf(const __hip_bfloat16* p)   { return __bfloat162float(*p); }
__device__ __forceinline__ void stf(float* p, float v)          { *p = v; }
__device__ __forceinline__ void stf(__hip_bfloat16* p, float v) { *p = __float2bfloat16(v); }

__device__ __forceinline__ float b2f(unsigned short u) { return __uint_as_float((unsigned)u << 16); }

// stage 4 consecutive channels (one vector global load) into 4 LDS channel-rows (f32)
__device__ __forceinline__ void stage4(float* dp, const __hip_bfloat16* gp) {
    ushort4 v = *reinterpret_cast<const ushort4*>(gp);
    dp[0]    = b2f(v.x);
    dp[SW]   = b2f(v.y);
    dp[2*SW] = b2f(v.z);
    dp[3*SW] = b2f(v.w);
}
__device__ __forceinline__ void stage4(float* dp, const float* gp) {
    float4 v = *reinterpret_cast<const float4*>(gp);
    dp[0] = v.x; dp[SW] = v.y; dp[2*SW] = v.z; dp[3*SW] = v.w;
}

// ---- dtype probe (FALLBACK ONLY — primary dispatch is host-side via in_sizes) ----
__global__ void probe_kernel(const unsigned int* __restrict__ s0w, int* __restrict__ flag) {
    __shared__ int cnt;
    if (threadIdx.x == 0) cnt = 0;
    __syncthreads();
    int local = 0;
    for (int i = threadIdx.x; i < 4096; i += 256) {
        unsigned int e = (s0w[i] >> 7) & 0xFF;
        if (e >= 118 && e <= 130) local++;
    }
    atomicAdd(&cnt, local);
    __syncthreads();
    if (threadIdx.x == 0) *flag = (cnt > 2048) ? 1 : 0;   // 1 = bf16, 0 = f32
}

template <typename T>
__global__ __launch_bounds__(NTH, 4)   // VGPR cap 64 — spill-free; 1024-blocks are 1/CU for any VGPR>32 (r3 analysis)
void diffusion_kernel(const T* __restrict__ s0,  const T* __restrict__ wg,  const T* __restrict__ wg1,
                      const T* __restrict__ g_gamma,  const T* __restrict__ g_beta,
                      const T* __restrict__ g_mean,   const T* __restrict__ g_var,
                      const T* __restrict__ g1_gamma, const T* __restrict__ g1_beta,
                      const T* __restrict__ g1_mean,  const T* __restrict__ g1_var,
                      const T* __restrict__ out_gamma, const T* __restrict__ out_beta,
                      const T* __restrict__ out_mean,  const T* __restrict__ out_var,
                      T* __restrict__ out,
                      const int* __restrict__ flag, int want)
{
    if (flag && *flag != want) return;   // dtype dispatch (fallback path only)

    __shared__ __align__(16) float s0sf[3*32*SW];            // 52992 B (f32 staging)
    __shared__ __align__(16) float hb0[28*HBS];              // 14784 B
    __shared__ __align__(16) float hb1[28*HBS];              // 14784 B
    __shared__ __align__(16) float g1b[28*128];              // 14336 B
    __shared__ float wgt[2][9][32];                          //  2304 B
    __shared__ float bnp[4][32];                             //   512 B
    __shared__ float obn[2][16];                             //   128 B
    // total ~99840 B — 1 block/CU (locked by VGPR pool anyway)

    #define S0S(r,j,w) s0sf[((r)*32 + (j))*SW + (w)]

    const int tid = threadIdx.x;
    const int bid = blockIdx.x;
    const int h     = bid & 127;
    const int bc    = bid >> 7;
    const int chunk = bc & 15;
    const int b     = bc >> 4;
    const int c0    = chunk << 4;

    const int   rT   = (h > 0)   ? h - 1 : 1;      // sobel reflect rows
    const int   rB   = (h < 127) ? h + 1 : 126;
    const float topf = (h > 0)   ? 1.f : 0.f;      // conv zero-pad flags (folded into weights)
    const float botf = (h < 127) ? 1.f : 0.f;

    // ---- stage s0: 3 rows x 32 ch x 128 w; 4-channel vector loads (3072 total, 3/thread) ----
    {
        const size_t base = (size_t)b * HN * WN * CN;
        #pragma unroll
        for (int k = 0; k < 3; ++k) {
            int e  = tid + k * NTH;                // < 3072
            int j4 = e & 7;                        // 4-channel group
            int w  = (e >> 3) & 127;
            int r  = e >> 10;                      // 0..2
            int row = (r == 0) ? rT : ((r == 1) ? h : rB);
            int cj  = (c0 - 8 + (j4 << 2)) & 255;  // group never straddles the wrap (4-aligned)
            stage4(&S0S(r, j4 << 2, w + 1), &s0[base + ((size_t)row * WN + w) * CN + cj]);
        }
    }
    if (tid < 192) {                               // zero pad columns (conv SAME)
        int r = tid >> 6, j = (tid >> 1) & 31, cp = (tid & 1) ? 129 : 0;
        S0S(r, j, cp) = 0.f;
    }
    if (tid < 288) {                               // weights, H-pad folded in
        int t9 = tid >> 5, j = tid & 31;
        int cj = (c0 - 8 + j) & 255;
        float rf = (t9 < 3) ? topf : ((t9 >= 6) ? botf : 1.f);
        wgt[0][t9][j] = ldf(&wg [t9*CN + cj]) * rf;
        wgt[1][t9][j] = ldf(&wg1[t9*CN + cj]) * rf;
    }
    if (tid < 32) {                                // folded BN params
        int cj = (c0 - 8 + tid) & 255;
        float s  = ldf(&g_gamma[cj])  * rsqrtf(ldf(&g_var[cj])  + EPSV);
        bnp[0][tid] = s;
        bnp[1][tid] = ldf(&g_beta[cj])  - ldf(&g_mean[cj])  * s;
        float s1 = ldf(&g1_gamma[cj]) * rsqrtf(ldf(&g1_var[cj]) + EPSV);
        bnp[2][tid] = s1;
        bnp[3][tid] = ldf(&g1_beta[cj]) - ldf(&g1_mean[cj]) * s1;
    }
    if (tid < 16) {
        int c = c0 + tid;
        float s = ldf(&out_gamma[c]) * rsqrtf(ldf(&out_var[c]) + EPSV);
        obn[0][tid] = s;
        obn[1][tid] = ldf(&out_beta[c]) - ldf(&out_mean[c]) * s;
    }
    __syncthreads();   // B1: staging complete

    // thread geometry: half-wave = one channel row, wq = quad index in W
    const int wq = tid & 31, l = tid >> 5, w0 = wq << 2;
    const int lane = tid & 63;
    const int sL = (lane & 32) | ((lane + 31) & 31);   // left rotate within half-wave (W wraps)
    const int sR = (lane & 32) | ((lane + 1)  & 31);
    const bool act = (l < 26);                         // coef/Jacobi rows

    // channel permutation: l<26 -> j=l+3 (coef rows), l=26 -> j=2 (low halo), l=27 -> j=29 (high halo)
    float4 ca0, caE, camx, capx, camy, capy, caS, bs4;
    float4 fs = make_float4(0.f, 0.f, 0.f, 0.f);
    int li = 0;

    if (tid < 896) {
        const int j = act ? l + 3 : ((l == 26) ? 2 : 29);
        li = act ? l + 1 : ((l == 26) ? 0 : 27);       // row in g1b / h-buffers

        // f32 LDS read of the 3x6 neighborhood (3 x float2 per row, 8B-aligned)
        float col[3][6];
        #pragma unroll
        for (int r = 0; r < 3; ++r) {
            float2 a = *(float2*)&S0S(r, j, w0);
            float2 c = *(float2*)&S0S(r, j, w0 + 2);
            float2 e = *(float2*)&S0S(r, j, w0 + 4);
            col[r][0] = a.x; col[r][1] = a.y;
            col[r][2] = c.x; col[r][3] = c.y;
            col[r][4] = e.x; col[r][5] = e.y;
        }

        // depthwise conv + BN + relu (both filters), 4 cells
        float gvk[4], g1vk[4];
        #pragma unroll
        for (int k = 0; k < 4; ++k) {
            float a = 0.f, a1 = 0.f;
            #pragma unroll
            for (int r = 0; r < 3; ++r)
                #pragma unroll
                for (int dx = 0; dx < 3; ++dx) {
                    float v = col[r][k + dx];
                    a  = fmaf(v, wgt[0][r*3 + dx][j], a);
                    a1 = fmaf(v, wgt[1][r*3 + dx][j], a1);
                }
            a  = fmaf(a,  bnp[0][j], bnp[1][j]);
            a1 = fmaf(a1, bnp[2][j], bnp[3][j]);
            gvk[k]  = fmaxf(a , 0.f);
            g1vk[k] = fmaxf(a1, 0.f);
        }
        *(float4*)&g1b[li*128 + w0] = make_float4(g1vk[0], g1vk[1], g1vk[2], g1vk[3]);

        // W-neighbor g via intra-wave shuffle (circular in W)
        float gL = __shfl(gvk[3], sL);
        float gR = __shfl(gvk[0], sR);

        fs = make_float4(col[1][1], col[1][2], col[1][3], col[1][4]);   // fsrc

        if (act) {
            // reflect overrides for sobel only (conv used the zero pads above)
            #pragma unroll
            for (int r = 0; r < 3; ++r) {
                col[r][0] = (wq == 0)  ? col[r][2] : col[r][0];
                col[r][5] = (wq == 31) ? col[r][3] : col[r][5];
            }
            float gXa[6], dY[6];
            #pragma unroll
            for (int c = 0; c < 6; ++c) {
                gXa[c] = col[0][c] + 2.f*col[1][c] + col[2][c];
                dY[c]  = col[2][c] - col[0][c];
            }
            float fsk[4] = {fs.x, fs.y, fs.z, fs.w};
            float uxk[4] = {0.5f*(gL     - gvk[1]), 0.5f*(gvk[0] - gvk[2]),
                            0.5f*(gvk[1] - gvk[3]), 0.5f*(gvk[2] - gR)};
            float o0[4], omx[4], opx[4], omy[4], opy[4], oS[4], oE[4], bsk[4];
            #pragma unroll
            for (int k = 0; k < 4; ++k) {
                float gy = dY[k] + 2.f*dY[k+1] + dY[k+2];
                float gx = gXa[k+2] - gXa[k];
                float Dx = __builtin_amdgcn_rcpf(fmaf(gy*gy, 0.25f, 1.f));   // 1 ulp rcp, tol 0.0625
                float Dy = __builtin_amdgcn_rcpf(fmaf(gx*gx, 0.25f, 1.f));
                float Bx = Dx*DTC, By = Dy*DTC;
                float s2 = 2.f*(Bx + By);
                float Dv = __builtin_amdgcn_rcpf(1.f + s2);
                float Ax = gvk[k]*DTC, Ay = g1vk[k]*DTC;
                o0[k]  = Dv*(1.f - s2);
                oS[k]  = Dv*(2.f*DTC)*fsk[k];
                omx[k] = Dv*(2.f*Bx - Ax);  opx[k] = Dv*(2.f*Bx + Ax);
                omy[k] = Dv*(2.f*By - Ay);  opy[k] = Dv*(2.f*By + Ay);
                bsk[k] = Dv*DTC;                     // scale for (g1u - g1d) term of caE
                oE[k]  = 2.f*bsk[k]*uxk[k];          // caE partial: 2*Dv*DTC*ux
            }
            ca0  = make_float4(o0[0],  o0[1],  o0[2],  o0[3]);
            camx = make_float4(omx[0], omx[1], omx[2], omx[3]);
            capx = make_float4(opx[0], opx[1], opx[2], opx[3]);
            camy = make_float4(omy[0], omy[1], omy[2], omy[3]);
            capy = make_float4(opy[0], opy[1], opy[2], opy[3]);
            caS  = make_float4(oS[0],  oS[1],  oS[2],  oS[3]);
            caE  = make_float4(oE[0],  oE[1],  oE[2],  oE[3]);
            bs4  = make_float4(bsk[0], bsk[1], bsk[2], bsk[3]);
        } else {
            // constant-fsrc halo rows (0, 27) of hb1 — hb0 halos come from the fill below
            *(float4*)&hb1[li*HBS + w0] = fs;
        }
        // pre-fill hb0 = h0 = fsrc for ALL 28 rows (replaces iteration-0 store; no overlay, so safe pre-barrier)
        *(float4*)&hb0[li*HBS + w0] = fs;
    }
    __syncthreads();   // B2 (merged): g1b + hb0(all rows) + hb1(halos) ready

    if (act) {
        float4 g1u = *(float4*)&g1b[(li-1)*128 + w0];   // channel - 1
        float4 g1d = *(float4*)&g1b[(li+1)*128 + w0];   // channel + 1
        // caE = 2*Dv*Ev = 2*Dv*DTC*ux + Dv*DTC*(g1u - g1d)
        caE.x = fmaf(bs4.x, g1u.x - g1d.x, caE.x);
        caE.y = fmaf(bs4.y, g1u.y - g1d.y, caE.y);
        caE.z = fmaf(bs4.z, g1u.z - g1d.z, caE.z);
        caE.w = fmaf(bs4.w, g1u.w - g1d.w, caE.w);
    }

    // ---- Jacobi: hc/h0 in registers; LDS carries up/dn row exchange ----
    float4 h0r = fs, hcr = fs;

    auto jstep = [&](float4 up, float4 dn) {
        float eL = __shfl(hcr.w, sL);                  // W-edge neighbors from registers
        float eR = __shfl(hcr.x, sR);
        float4 nw;
        {
            float t = fmaf(ca0.x, h0r.x, caS.x);
            t = fmaf(-caE.x, hcr.x, t);
            t = fmaf(camx.x, eL,    t);
            t = fmaf(capx.x, hcr.y, t);
            t = fmaf(camy.x, up.x,  t);
            nw.x = fmaf(capy.x, dn.x, t);
        }
        {
            float t = fmaf(ca0.y, h0r.y, caS.y);
            t = fmaf(-caE.y, hcr.y, t);
            t = fmaf(camx.y, hcr.x, t);
            t = fmaf(capx.y, hcr.z, t);
            t = fmaf(camy.y, up.y,  t);
            nw.y = fmaf(capy.y, dn.y, t);
        }
        {
            float t = fmaf(ca0.z, h0r.z, caS.z);
            t = fmaf(-caE.z, hcr.z, t);
            t = fmaf(camx.z, hcr.y, t);
            t = fmaf(capx.z, hcr.w, t);
            t = fmaf(camy.z, up.z,  t);
            nw.z = fmaf(capy.z, dn.z, t);
        }
        {
            float t = fmaf(ca0.w, h0r.w, caS.w);
            t = fmaf(-caE.w, hcr.w, t);
            t = fmaf(camx.w, hcr.z, t);
            t = fmaf(capx.w, eR,    t);
            t = fmaf(camy.w, up.w,  t);
            nw.w = fmaf(capy.w, dn.w, t);
        }
        h0r = hcr; hcr = nw;
    };

    // n = 0: hb0 already holds h0 (pre-filled) — no store, no extra barrier
    if (act) {
        float4 up = *(float4*)&hb0[(li-1)*HBS + w0];
        float4 dn = *(float4*)&hb0[(li+1)*HBS + w0];
        jstep(up, dn);
    }
    // n = 1..4
    #pragma unroll
    for (int n = 1; n < 5; ++n) {
        float* hb = (n & 1) ? hb1 : hb0;
        if (act) *(float4*)&hb[li*HBS + w0] = hcr;
        __syncthreads();                               // B3..B6
        if (act) {
            float4 up = *(float4*)&hb[(li-1)*HBS + w0];
            float4 dn = *(float4*)&hb[(li+1)*HBS + w0];
            jstep(up, dn);
        }
    }
    // publish h5 into hb1 (hb1's last reads were before the n=4 barrier -> safe)
    if (act) *(float4*)&hb1[li*HBS + w0] = hcr;
    __syncthreads();   // B7

    // ---- out = relu(bn(h)) on the 16 core channels; all 1024 threads, 2 cells each ----
    {
        int i16 = tid & 15, w2 = (tid >> 4) << 1;      // w2 in 0..126
        float2 v = *(float2*)&hb1[(i16 + 6)*HBS + w2];
        float sc = obn[0][i16], bi = obn[1][i16];
        size_t ob = (((size_t)b*HN + h)*WN + w2)*CN + (c0 + i16);
        stf(&out[ob],      fmaxf(fmaf(v.x, sc, bi), 0.f));
        stf(&out[ob + CN], fmaxf(fmaf(v.y, sc, bi), 0.f));
    }
    #undef S0S
}

extern "C" void kernel_launch(void* const* d_in, const int* in_sizes, int n_in,
                              void* d_out, int out_size, void* d_ws, size_t ws_size,
                              hipStream_t stream) {
    dim3 grid(BN * 16 * HN);   // 16384 blocks

    // Host-side dtype dispatch from s0's byte size (single dispatch, no probe).
    const long long nb    = (n_in > 0) ? (long long)in_sizes[0] : 0;
    const long long F32B  = (long long)BN * HN * WN * CN * 4;   // 134217728
    const long long BF16B = F32B / 2;                           //  67108864

    if (nb == F32B) {
        diffusion_kernel<float><<<grid, NTH, 0, stream>>>(
            (const float*)d_in[0], (const float*)d_in[1], (const float*)d_in[2],
            (const float*)d_in[3], (const float*)d_in[4], (const float*)d_in[5], (const float*)d_in[6],
            (const float*)d_in[7], (const float*)d_in[8], (const float*)d_in[9], (const float*)d_in[10],
            (const float*)d_in[11], (const float*)d_in[12], (const float*)d_in[13], (const float*)d_in[14],
            (float*)d_out, nullptr, 0);
    } else if (nb == BF16B) {
        diffusion_kernel<__hip_bfloat16><<<grid, NTH, 0, stream>>>(
            (const __hip_bfloat16*)d_in[0], (const __hip_bfloat16*)d_in[1], (const __hip_bfloat16*)d_in[2],
            (const __hip_bfloat16*)d_in[3], (const __hip_bfloat16*)d_in[4], (const __hip_bfloat16*)d_in[5], (const __hip_bfloat16*)d_in[6],
            (const __hip_bfloat16*)d_in[7], (const __hip_bfloat16*)d_in[8], (const __hip_bfloat16*)d_in[9], (const __hip_bfloat16*)d_in[10],
            (const __hip_bfloat16*)d_in[11], (const __hip_bfloat16*)d_in[12], (const __hip_bfloat16*)d_in[13], (const __hip_bfloat16*)d_in[14],
            (__hip_bfloat16*)d_out, nullptr, 0);
    } else if (ws_size >= 4) {
        // Fallback: device-side probe + dual dispatch (sizes ambiguous)
        int* flag = (int*)d_ws;
        probe_kernel<<<1, 256, 0, stream>>>((const unsigned int*)d_in[0], flag);

        diffusion_kernel<float><<<grid, NTH, 0, stream>>>(
            (const float*)d_in[0], (const float*)d_in[1], (const float*)d_in[2],
            (const float*)d_in[3], (const float*)d_in[4], (const float*)d_in[5], (const float*)d_in[6],
            (const float*)d_in[7], (const float*)d_in[8], (const float*)d_in[9], (const float*)d_in[10],
            (const float*)d_in[11], (const float*)d_in[12], (const float*)d_in[13], (const float*)d_in[14],
            (float*)d_out, flag, 0);

        diffusion_kernel<__hip_bfloat16><<<grid, NTH, 0, stream>>>(
            (const __hip_bfloat16*)d_in[0], (const __hip_bfloat16*)d_in[1], (const __hip_bfloat16*)d_in[2],
            (const __hip_bfloat16*)d_in[3], (const __hip_bfloat16*)d_in[4], (const __hip_bfloat16*)d_in[5], (const __hip_bfloat16*)d_in[6],
            (const __hip_bfloat16*)d_in[7], (const __hip_bfloat16*)d_in[8], (const __hip_bfloat16*)d_in[9], (const __hip_bfloat16*)d_in[10],
            (const __hip_bfloat16*)d_in[11], (const __hip_bfloat16*)d_in[12], (const __hip_bfloat16*)d_in[13], (const __hip_bfloat16*)d_in[14],
            (__hip_bfloat16*)d_out, flag, 1);
    } else {
        diffusion_kernel<float><<<grid, NTH, 0, stream>>>(
            (const float*)d_in[0], (const float*)d_in[1], (const float*)d_in[2],
            (const float*)d_in[3], (const float*)d_in[4], (const float*)d_in[5], (const float*)d_in[6],
            (const float*)d_in[7], (const float*)d_in[8], (const float*)d_in[9], (const float*)d_in[10],
            (const float*)d_in[11], (const float*)d_in[12], (const float*)d_in[13], (const float*)d_in[14],
            (float*)d_out, nullptr, 0);
    }
}

// Round 5
// 571.373 us; speedup vs baseline: 1.1446x; 1.1446x over previous
//
#include <hip/hip_runtime.h>
#include <hip/hip_bf16.h>

#define BN 8
#define HN 128
#define WN 128
#define CN 256
#define DTC 0.2f
#define EPSV 1e-3f
#define NTH 1024

#define SJ 32      // staged channel rows (phys j: cj = c0-8+j)
#define SW 134     // w stride: col0 & col129 are zero pads, data at 1..128

// ---- dtype-generic helpers (compute stays f32) ----
__device__ __forceinline__ float ldf(const float* p)            { return *p; }
__device__ __forceinline__ float ldf(const __hip_bfloat16* p)   { return __bfloat162float(*p); }
__device__ __forceinline__ __hip_bfloat16 ldb(const float* p)          { return __float2bfloat16(*p); }
__device__ __forceinline__ __hip_bfloat16 ldb(const __hip_bfloat16* p) { return *p; }
__device__ __forceinline__ void stf(float* p, float v)          { *p = v; }
__device__ __forceinline__ void stf(__hip_bfloat16* p, float v) { *p = __float2bfloat16(v); }

// ---- dtype probe (FALLBACK ONLY — primary dispatch is host-side via in_sizes) ----
__global__ void probe_kernel(const unsigned int* __restrict__ s0w, int* __restrict__ flag) {
    __shared__ int cnt;
    if (threadIdx.x == 0) cnt = 0;
    __syncthreads();
    int local = 0;
    for (int i = threadIdx.x; i < 4096; i += 256) {
        unsigned int e = (s0w[i] >> 7) & 0xFF;
        if (e >= 118 && e <= 130) local++;
    }
    atomicAdd(&cnt, local);
    __syncthreads();
    if (threadIdx.x == 0) *flag = (cnt > 2048) ? 1 : 0;   // 1 = bf16, 0 = f32
}

__device__ __forceinline__ void mkcoef(float gy, float gx, float gg, float g11,
                                       float gl, float gr, float g1u, float g1d, float fsrc,
                                       float& o0, float& oE, float& omx, float& opx,
                                       float& omy, float& opy, float& oS)
{
    // v_rcp_f32 (1 ulp) instead of IEEE div sequence — tol 0.0625, register-reducing
    float Dx = __builtin_amdgcn_rcpf(fmaf(gy*gy, 0.25f, 1.f));
    float Dy = __builtin_amdgcn_rcpf(fmaf(gx*gx, 0.25f, 1.f));
    float ux = 0.5f * (gl - gr);
    float vy = 0.5f * (g1u - g1d);
    float Ax = gg*DTC, Ay = g11*DTC;
    float Bx = Dx*DTC, By = Dy*DTC;
    float Ev = (ux + vy)*DTC;
    float s2 = 2.f*(Bx + By);
    float Dv = __builtin_amdgcn_rcpf(1.f + s2);
    o0  = Dv*(1.f - s2);
    oE  = 2.f*Dv*Ev;
    omx = Dv*(2.f*Bx - Ax);
    opx = Dv*(2.f*Bx + Ax);
    omy = Dv*(2.f*By - Ay);
    opy = Dv*(2.f*By + Ay);
    oS  = Dv*(2.f*DTC)*fsrc;
}

template <typename T>
__global__ __launch_bounds__(NTH, 8)   // cap VGPR at 32: 8 waves/SIMD -> TWO 16-wave blocks/CU (r0 proven 28 with heavier div code)
void diffusion_kernel(const T* __restrict__ s0,  const T* __restrict__ wg,  const T* __restrict__ wg1,
                      const T* __restrict__ g_gamma,  const T* __restrict__ g_beta,
                      const T* __restrict__ g_mean,   const T* __restrict__ g_var,
                      const T* __restrict__ g1_gamma, const T* __restrict__ g1_beta,
                      const T* __restrict__ g1_mean,  const T* __restrict__ g1_var,
                      const T* __restrict__ out_gamma, const T* __restrict__ out_beta,
                      const T* __restrict__ out_mean,  const T* __restrict__ out_var,
                      T* __restrict__ out,
                      const int* __restrict__ flag, int want)
{
    if (flag && *flag != want) return;   // dtype dispatch (fallback path only)

    __shared__ __hip_bfloat16 s0s[3][SJ][SW];      // 25728 B
    __shared__ float wgt[2][9][SJ];                //  2304 B
    __shared__ float bnp[4][SJ];                   //   512 B
    __shared__ float obn[2][16];                   //   128 B
    __shared__ __align__(16) float r2[2*28*128];   // 28672 B : gb/g1b then hA/hB

    const int tid = threadIdx.x;
    const int bid = blockIdx.x;
    const int h     = bid & 127;
    const int bc    = bid >> 7;
    const int chunk = bc & 15;
    const int b     = bc >> 4;
    const int c0    = chunk << 4;

    const int   rT   = (h > 0)   ? h - 1 : 1;      // sobel reflect rows
    const int   rB   = (h < 127) ? h + 1 : 126;
    const float topf = (h > 0)   ? 1.f : 0.f;      // conv zero-pad flags
    const float botf = (h < 127) ? 1.f : 0.f;

    // ---- stage s0: 3 rows x 32 ch x 128 w, coalesced over channels ----
    {
        const size_t base = (size_t)b * HN * WN * CN;
        #pragma unroll
        for (int k = 0; k < 12; ++k) {
            int e = tid + k*NTH;                   // < 12288
            int j = e & 31;
            int w = (e >> 5) & 127;
            int r = e >> 12;
            int row = (r == 0) ? rT : ((r == 1) ? h : rB);
            int cj  = (c0 - 8 + j) & 255;
            s0s[r][j][w+1] = ldb(&s0[base + ((size_t)row*WN + w)*CN + cj]);
        }
    }
    if (tid < 192) {                               // zero pad columns
        int r = tid >> 6, j = (tid >> 1) & 31, cp = (tid & 1) ? 129 : 0;
        s0s[r][j][cp] = __float2bfloat16(0.f);
    }
    if (tid < 288) {                               // weights, H-pad folded in
        int t9 = tid >> 5, j = tid & 31;
        int cj = (c0 - 8 + j) & 255;
        float rf = (t9 < 3) ? topf : ((t9 >= 6) ? botf : 1.f);
        wgt[0][t9][j] = ldf(&wg [t9*CN + cj]) * rf;
        wgt[1][t9][j] = ldf(&wg1[t9*CN + cj]) * rf;
    }
    if (tid < 32) {                                // folded BN params
        int cj = (c0 - 8 + tid) & 255;
        float s  = ldf(&g_gamma[cj])  * rsqrtf(ldf(&g_var[cj])  + EPSV);
        bnp[0][tid] = s;
        bnp[1][tid] = ldf(&g_beta[cj])  - ldf(&g_mean[cj])  * s;
        float s1 = ldf(&g1_gamma[cj]) * rsqrtf(ldf(&g1_var[cj]) + EPSV);
        bnp[2][tid] = s1;
        bnp[3][tid] = ldf(&g1_beta[cj]) - ldf(&g1_mean[cj]) * s1;
    }
    if (tid < 16) {
        int c = c0 + tid;
        float s = ldf(&out_gamma[c]) * rsqrtf(ldf(&out_var[c]) + EPSV);
        obn[0][tid] = s;
        obn[1][tid] = ldf(&out_beta[c]) - ldf(&out_mean[c]) * s;
    }
    __syncthreads();

    float* gb  = r2;            // [28][128]
    float* g1b = r2 + 3584;

    // ---- pass 1: depthwise conv + BN + relu, one quad (4 w) per thread ----
    if (tid < 896) {            // 28 rows x 32 quads
        int wq = tid & 31, l = tid >> 5, j = l + 2, w0 = wq << 2;
        float col[3][6];
        #pragma unroll
        for (int r = 0; r < 3; ++r)
            #pragma unroll
            for (int c = 0; c < 6; ++c)
                col[r][c] = __bfloat162float(s0s[r][j][w0 + c]);  // phys cols w0..w0+5
        float gvk[4], g1vk[4];
        #pragma unroll
        for (int k = 0; k < 4; ++k) {
            float a = 0.f, a1 = 0.f;
            #pragma unroll
            for (int r = 0; r < 3; ++r)
                #pragma unroll
                for (int dx = 0; dx < 3; ++dx) {
                    float v = col[r][k + dx];
                    a  += v * wgt[0][r*3+dx][j];
                    a1 += v * wgt[1][r*3+dx][j];
                }
            a  = a  * bnp[0][j] + bnp[1][j];
            a1 = a1 * bnp[2][j] + bnp[3][j];
            gvk[k]  = fmaxf(a , 0.f);
            g1vk[k] = fmaxf(a1, 0.f);
        }
        float4 gv  = make_float4(gvk[0],  gvk[1],  gvk[2],  gvk[3]);
        float4 g1v = make_float4(g1vk[0], g1vk[1], g1vk[2], g1vk[3]);
        *(float4*)&gb [l*128 + w0] = gv;
        *(float4*)&g1b[l*128 + w0] = g1v;
    }
    __syncthreads();

    // ---- pass 2: per-cell coefficients into float4 registers ----
    float4 ca0, caE, camx, capx, camy, capy, caS, fs;
    const int wq = tid & 31, ci = tid >> 5, w0 = wq << 2;  // ci in 0..25 for active
    const bool act = (tid < 832);                          // 26 rows x 32 quads
    if (act) {
        int li = ci + 1, j = ci + 3;
        float ct[6], cm[6], cb[6], gX[6];
        #pragma unroll
        for (int c6 = 0; c6 < 6; ++c6) {
            int c  = w0 - 1 + c6;
            int pc = min(abs(c), 254 - c);     // reflect in W
            int ph = pc + 1;
            ct[c6] = __bfloat162float(s0s[0][j][ph]);
            cm[c6] = __bfloat162float(s0s[1][j][ph]);
            cb[c6] = __bfloat162float(s0s[2][j][ph]);
            gX[c6] = ct[c6] + 2.f*cm[c6] + cb[c6];
        }
        float4 gc  = *(float4*)&gb [li*128 + w0];
        float  gL  = gb[li*128 + ((w0 - 1) & 127)];
        float  gR  = gb[li*128 + ((w0 + 4) & 127)];
        float4 g1c = *(float4*)&g1b[li*128 + w0];
        float4 g1u = *(float4*)&g1b[(li-1)*128 + w0];
        float4 g1d = *(float4*)&g1b[(li+1)*128 + w0];
        fs = make_float4(cm[1], cm[2], cm[3], cm[4]);

        #define GY(K) ((cb[K] + 2.f*cb[K+1] + cb[K+2]) - (ct[K] + 2.f*ct[K+1] + ct[K+2]))
        mkcoef(GY(0), gX[2]-gX[0], gc.x, g1c.x, gL,   gc.y, g1u.x, g1d.x, fs.x,
               ca0.x, caE.x, camx.x, capx.x, camy.x, capy.x, caS.x);
        mkcoef(GY(1), gX[3]-gX[1], gc.y, g1c.y, gc.x, gc.z, g1u.y, g1d.y, fs.y,
               ca0.y, caE.y, camx.y, capx.y, camy.y, capy.y, caS.y);
        mkcoef(GY(2), gX[4]-gX[2], gc.z, g1c.z, gc.y, gc.w, g1u.z, g1d.z, fs.z,
               ca0.z, caE.z, camx.z, capx.z, camy.z, capy.z, caS.z);
        mkcoef(GY(3), gX[5]-gX[3], gc.w, g1c.w, gc.z, gR,   g1u.w, g1d.w, fs.w,
               ca0.w, caE.w, camx.w, capx.w, camy.w, capy.w, caS.w);
        #undef GY
    }
    __syncthreads();   // gb/g1b reads done; r2 becomes hA/hB

    // ---- pass 3: init h buffers (h = h0 = fsrc); rows 0,27 are pads ----
    if (act) {
        *(float4*)&r2[(ci+1)*128 + w0]        = fs;   // hA
        *(float4*)&r2[3584 + (ci+1)*128 + w0] = fs;   // hB
    }
    __syncthreads();

    // ---- pass 4: 5 Jacobi iterations, all-immediate LDS addressing ----
    float* bU = &r2[ci*128 + w0];                      // row above (c-1)
    float* bM = &r2[(ci+1)*128 + ((w0 - 1) & 127)];    // left edge (circular)
    float* bP = &r2[(ci+1)*128 + ((w0 + 4) & 127)];    // right edge
    #pragma unroll
    for (int n = 0; n < 5; ++n) {
        const int co = (n & 1) ? 0 : 3584;   // cur buffer float offset
        const int po = 3584 - co;            // prv (receives h_{n+1})
        if (act) {
            float4 up = *(float4*)(bU + co);
            float4 hc = *(float4*)(bU + co + 128);
            float4 dn = *(float4*)(bU + co + 256);
            float4 h0 = *(float4*)(bU + po + 128);
            float  eL = bM[co];
            float  eR = bP[co];
            float4 nw;
            nw.x = ca0.x*h0.x - caE.x*hc.x + camx.x*eL   + capx.x*hc.y + camy.x*up.x + capy.x*dn.x + caS.x;
            nw.y = ca0.y*h0.y - caE.y*hc.y + camx.y*hc.x + capx.y*hc.z + camy.y*up.y + capy.y*dn.y + caS.y;
            nw.z = ca0.z*h0.z - caE.z*hc.z + camx.z*hc.y + capx.z*hc.w + camy.z*up.z + capy.z*dn.z + caS.z;
            nw.w = ca0.w*h0.w - caE.w*hc.w + camx.w*hc.z + capx.w*eR   + camy.w*up.w + capy.w*dn.w + caS.w;
            *(float4*)(bU + po + 128) = nw;
        }
        __syncthreads();
    }
    // final h is in hA = r2 (rows 1..26)

    // ---- pass 5: out = relu(bn(h)) on the 16 core channels ----
    if (tid < 512) {
        int i16 = tid & 15, w5 = ((tid >> 4) & 31) << 2;
        float4 v = *(float4*)&r2[(i16 + 6)*128 + w5];
        float sc = obn[0][i16], bi = obn[1][i16];
        size_t ob = (((size_t)b*HN + h)*WN + w5)*CN + (c0 + i16);
        stf(&out[ob],          fmaxf(v.x*sc + bi, 0.f));
        stf(&out[ob + CN],     fmaxf(v.y*sc + bi, 0.f));
        stf(&out[ob + 2*CN],   fmaxf(v.z*sc + bi, 0.f));
        stf(&out[ob + 3*CN],   fmaxf(v.w*sc + bi, 0.f));
    }
}

extern "C" void kernel_launch(void* const* d_in, const int* in_sizes, int n_in,
                              void* d_out, int out_size, void* d_ws, size_t ws_size,
                              hipStream_t stream) {
    dim3 grid(BN * 16 * HN);   // 16384 blocks

    // Host-side dtype dispatch from s0's byte size (single dispatch, no probe/dummy).
    const long long nb    = (n_in > 0) ? (long long)in_sizes[0] : 0;
    const long long F32B  = (long long)BN * HN * WN * CN * 4;   // 134217728
    const long long BF16B = F32B / 2;                           //  67108864

    if (nb == F32B) {
        diffusion_kernel<float><<<grid, NTH, 0, stream>>>(
            (const float*)d_in[0], (const float*)d_in[1], (const float*)d_in[2],
            (const float*)d_in[3], (const float*)d_in[4], (const float*)d_in[5], (const float*)d_in[6],
            (const float*)d_in[7], (const float*)d_in[8], (const float*)d_in[9], (const float*)d_in[10],
            (const float*)d_in[11], (const float*)d_in[12], (const float*)d_in[13], (const float*)d_in[14],
            (float*)d_out, nullptr, 0);
    } else if (nb == BF16B) {
        diffusion_kernel<__hip_bfloat16><<<grid, NTH, 0, stream>>>(
            (const __hip_bfloat16*)d_in[0], (const __hip_bfloat16*)d_in[1], (const __hip_bfloat16*)d_in[2],
            (const __hip_bfloat16*)d_in[3], (const __hip_bfloat16*)d_in[4], (const __hip_bfloat16*)d_in[5], (const __hip_bfloat16*)d_in[6],
            (const __hip_bfloat16*)d_in[7], (const __hip_bfloat16*)d_in[8], (const __hip_bfloat16*)d_in[9], (const __hip_bfloat16*)d_in[10],
            (const __hip_bfloat16*)d_in[11], (const __hip_bfloat16*)d_in[12], (const __hip_bfloat16*)d_in[13], (const __hip_bfloat16*)d_in[14],
            (__hip_bfloat16*)d_out, nullptr, 0);
    } else if (ws_size >= 4) {
        // Fallback: device-side probe + dual dispatch (sizes ambiguous)
        int* flag = (int*)d_ws;
        probe_kernel<<<1, 256, 0, stream>>>((const unsigned int*)d_in[0], flag);

        diffusion_kernel<float><<<grid, NTH, 0, stream>>>(
            (const float*)d_in[0], (const float*)d_in[1], (const float*)d_in[2],
            (const float*)d_in[3], (const float*)d_in[4], (const float*)d_in[5], (const float*)d_in[6],
            (const float*)d_in[7], (const float*)d_in[8], (const float*)d_in[9], (const float*)d_in[10],
            (const float*)d_in[11], (const float*)d_in[12], (const float*)d_in[13], (const float*)d_in[14],
            (float*)d_out, flag, 0);

        diffusion_kernel<__hip_bfloat16><<<grid, NTH, 0, stream>>>(
            (const __hip_bfloat16*)d_in[0], (const __hip_bfloat16*)d_in[1], (const __hip_bfloat16*)d_in[2],
            (const __hip_bfloat16*)d_in[3], (const __hip_bfloat16*)d_in[4], (const __hip_bfloat16*)d_in[5], (const __hip_bfloat16*)d_in[6],
            (const __hip_bfloat16*)d_in[7], (const __hip_bfloat16*)d_in[8], (const __hip_bfloat16*)d_in[9], (const __hip_bfloat16*)d_in[10],
            (const __hip_bfloat16*)d_in[11], (const __hip_bfloat16*)d_in[12], (const __hip_bfloat16*)d_in[13], (const __hip_bfloat16*)d_in[14],
            (__hip_bfloat16*)d_out, flag, 1);
    } else {
        diffusion_kernel<float><<<grid, NTH, 0, stream>>>(
            (const float*)d_in[0], (const float*)d_in[1], (const float*)d_in[2],
            (const float*)d_in[3], (const float*)d_in[4], (const float*)d_in[5], (const float*)d_in[6],
            (const float*)d_in[7], (const float*)d_in[8], (const float*)d_in[9], (const float*)d_in[10],
            (const float*)d_in[11], (const float*)d_in[12], (const float*)d_in[13], (const float*)d_in[14],
            (float*)d_out, nullptr, 0);
    }
}

// Round 6
// 540.201 us; speedup vs baseline: 1.2107x; 1.0577x over previous
//
#include <hip/hip_runtime.h>
#include <hip/hip_bf16.h>

#define BN 8
#define HN 128
#define WN 128
#define CN 256
#define DTC 0.2f
#define EPSV 1e-3f
#define NTH 1024

#define SJ 32      // staged channel rows (phys j: cj = c0-8+j)
#define SW 134     // w stride: col0 & col129 are zero pads, data at 1..128

// ---- dtype-generic helpers (compute stays f32) ----
__device__ __forceinline__ float ldf(const float* p)            { return *p; }
__device__ __forceinline__ float ldf(const __hip_bfloat16* p)   { return __bfloat162float(*p); }
__device__ __forceinline__ __hip_bfloat16 ldb(const float* p)          { return __float2bfloat16(*p); }
__device__ __forceinline__ __hip_bfloat16 ldb(const __hip_bfloat16* p) { return *p; }
__device__ __forceinline__ void stf(float* p, float v)          { *p = v; }
__device__ __forceinline__ void stf(__hip_bfloat16* p, float v) { *p = __float2bfloat16(v); }

// ---- dtype probe: bf16 exponent band test on raw u32 words ----
__global__ void probe_kernel(const unsigned int* __restrict__ s0w, int* __restrict__ flag) {
    __shared__ int cnt;
    if (threadIdx.x == 0) cnt = 0;
    __syncthreads();
    int local = 0;
    for (int i = threadIdx.x; i < 4096; i += 256) {
        unsigned int e = (s0w[i] >> 7) & 0xFF;
        if (e >= 118 && e <= 130) local++;
    }
    atomicAdd(&cnt, local);
    __syncthreads();
    if (threadIdx.x == 0) *flag = (cnt > 2048) ? 1 : 0;   // 1 = bf16, 0 = f32
}

__device__ __forceinline__ void mkcoef(float gy, float gx, float gg, float g11,
                                       float gl, float gr, float g1u, float g1d, float fsrc,
                                       float& o0, float& oE, float& omx, float& opx,
                                       float& omy, float& opy, float& oS)
{
    float Dx = 1.f / (gy*gy*0.25f + 1.f);
    float Dy = 1.f / (gx*gx*0.25f + 1.f);
    float ux = 0.5f * (gl - gr);
    float vy = 0.5f * (g1u - g1d);
    float Ax = gg*DTC, Ay = g11*DTC;
    float Bx = Dx*DTC, By = Dy*DTC;
    float Ev = (ux + vy)*DTC;
    float Dv = 1.f / (1.f + 2.f*Bx + 2.f*By);
    o0  = Dv*(1.f - 2.f*Bx - 2.f*By);
    oE  = 2.f*Dv*Ev;
    omx = Dv*(2.f*Bx - Ax);
    opx = Dv*(2.f*Bx + Ax);
    omy = Dv*(2.f*By - Ay);
    opy = Dv*(2.f*By + Ay);
    oS  = Dv*(2.f*DTC)*fsrc;
}

// Shared-memory block hoisted into a struct so the runtime-branched kernel
// allocates it ONCE (57344 B), not once per dtype instantiation.
struct SmemT {
    __hip_bfloat16 s0s[3][SJ][SW];                 // 25728 B
    float wgt[2][9][SJ];                           //  2304 B
    float bnp[4][SJ];                              //   512 B
    float obn[2][16];                              //   128 B
    __attribute__((aligned(16))) float r2[2*28*128];  // 28672 B : gb/g1b then hA/hB
};                                                 // total 57344 B

template <typename T>
__device__ __forceinline__
void diffusion_body(SmemT& sm,
                    const T* __restrict__ s0,  const T* __restrict__ wg,  const T* __restrict__ wg1,
                    const T* __restrict__ g_gamma,  const T* __restrict__ g_beta,
                    const T* __restrict__ g_mean,   const T* __restrict__ g_var,
                    const T* __restrict__ g1_gamma, const T* __restrict__ g1_beta,
                    const T* __restrict__ g1_mean,  const T* __restrict__ g1_var,
                    const T* __restrict__ out_gamma, const T* __restrict__ out_beta,
                    const T* __restrict__ out_mean,  const T* __restrict__ out_var,
                    T* __restrict__ out)
{
    float* r2 = sm.r2;

    const int tid = threadIdx.x;
    const int bid = blockIdx.x;
    const int h     = bid & 127;
    const int bc    = bid >> 7;
    const int chunk = bc & 15;
    const int b     = bc >> 4;
    const int c0    = chunk << 4;

    const int   rT   = (h > 0)   ? h - 1 : 1;      // sobel reflect rows
    const int   rB   = (h < 127) ? h + 1 : 126;
    const float topf = (h > 0)   ? 1.f : 0.f;      // conv zero-pad flags
    const float botf = (h < 127) ? 1.f : 0.f;

    // ---- stage s0: 3 rows x 32 ch x 128 w, coalesced over channels ----
    {
        const size_t base = (size_t)b * HN * WN * CN;
        #pragma unroll
        for (int k = 0; k < 12; ++k) {
            int e = tid + k*NTH;                   // < 12288
            int j = e & 31;
            int w = (e >> 5) & 127;
            int r = e >> 12;
            int row = (r == 0) ? rT : ((r == 1) ? h : rB);
            int cj  = (c0 - 8 + j) & 255;
            sm.s0s[r][j][w+1] = ldb(&s0[base + ((size_t)row*WN + w)*CN + cj]);
        }
    }
    if (tid < 192) {                               // zero pad columns
        int r = tid >> 6, j = (tid >> 1) & 31, cp = (tid & 1) ? 129 : 0;
        sm.s0s[r][j][cp] = __float2bfloat16(0.f);
    }
    if (tid < 288) {                               // weights, H-pad folded in
        int t9 = tid >> 5, j = tid & 31;
        int cj = (c0 - 8 + j) & 255;
        float rf = (t9 < 3) ? topf : ((t9 >= 6) ? botf : 1.f);
        sm.wgt[0][t9][j] = ldf(&wg [t9*CN + cj]) * rf;
        sm.wgt[1][t9][j] = ldf(&wg1[t9*CN + cj]) * rf;
    }
    if (tid < 32) {                                // folded BN params
        int cj = (c0 - 8 + tid) & 255;
        float s  = ldf(&g_gamma[cj])  * rsqrtf(ldf(&g_var[cj])  + EPSV);
        sm.bnp[0][tid] = s;
        sm.bnp[1][tid] = ldf(&g_beta[cj])  - ldf(&g_mean[cj])  * s;
        float s1 = ldf(&g1_gamma[cj]) * rsqrtf(ldf(&g1_var[cj]) + EPSV);
        sm.bnp[2][tid] = s1;
        sm.bnp[3][tid] = ldf(&g1_beta[cj]) - ldf(&g1_mean[cj]) * s1;
    }
    if (tid < 16) {
        int c = c0 + tid;
        float s = ldf(&out_gamma[c]) * rsqrtf(ldf(&out_var[c]) + EPSV);
        sm.obn[0][tid] = s;
        sm.obn[1][tid] = ldf(&out_beta[c]) - ldf(&out_mean[c]) * s;
    }
    __syncthreads();

    float* gb  = r2;            // [28][128]
    float* g1b = r2 + 3584;

    // ---- pass 1: depthwise conv + BN + relu, one quad (4 w) per thread ----
    if (tid < 896) {            // 28 rows x 32 quads
        int wq = tid & 31, l = tid >> 5, j = l + 2, w0 = wq << 2;
        float col[3][6];
        #pragma unroll
        for (int r = 0; r < 3; ++r)
            #pragma unroll
            for (int c = 0; c < 6; ++c)
                col[r][c] = __bfloat162float(sm.s0s[r][j][w0 + c]);  // phys cols w0..w0+5
        float gvk[4], g1vk[4];
        #pragma unroll
        for (int k = 0; k < 4; ++k) {
            float a = 0.f, a1 = 0.f;
            #pragma unroll
            for (int r = 0; r < 3; ++r)
                #pragma unroll
                for (int dx = 0; dx < 3; ++dx) {
                    float v = col[r][k + dx];
                    a  += v * sm.wgt[0][r*3+dx][j];
                    a1 += v * sm.wgt[1][r*3+dx][j];
                }
            a  = a  * sm.bnp[0][j] + sm.bnp[1][j];
            a1 = a1 * sm.bnp[2][j] + sm.bnp[3][j];
            gvk[k]  = fmaxf(a , 0.f);
            g1vk[k] = fmaxf(a1, 0.f);
        }
        float4 gv  = make_float4(gvk[0],  gvk[1],  gvk[2],  gvk[3]);
        float4 g1v = make_float4(g1vk[0], g1vk[1], g1vk[2], g1vk[3]);
        *(float4*)&gb [l*128 + w0] = gv;
        *(float4*)&g1b[l*128 + w0] = g1v;
    }
    __syncthreads();

    // ---- pass 2: per-cell coefficients into float4 registers ----
    float4 ca0, caE, camx, capx, camy, capy, caS, fs;
    const int wq = tid & 31, ci = tid >> 5, w0 = wq << 2;  // ci in 0..25 for active
    const bool act = (tid < 832);                          // 26 rows x 32 quads
    if (act) {
        int li = ci + 1, j = ci + 3;
        float ct[6], cm[6], cb[6], gX[6];
        #pragma unroll
        for (int c6 = 0; c6 < 6; ++c6) {
            int c  = w0 - 1 + c6;
            int pc = min(abs(c), 254 - c);     // reflect in W
            int ph = pc + 1;
            ct[c6] = __bfloat162float(sm.s0s[0][j][ph]);
            cm[c6] = __bfloat162float(sm.s0s[1][j][ph]);
            cb[c6] = __bfloat162float(sm.s0s[2][j][ph]);
            gX[c6] = ct[c6] + 2.f*cm[c6] + cb[c6];
        }
        float4 gc  = *(float4*)&gb [li*128 + w0];
        float  gL  = gb[li*128 + ((w0 - 1) & 127)];
        float  gR  = gb[li*128 + ((w0 + 4) & 127)];
        float4 g1c = *(float4*)&g1b[li*128 + w0];
        float4 g1u = *(float4*)&g1b[(li-1)*128 + w0];
        float4 g1d = *(float4*)&g1b[(li+1)*128 + w0];
        fs = make_float4(cm[1], cm[2], cm[3], cm[4]);

        #define GY(K) ((cb[K] + 2.f*cb[K+1] + cb[K+2]) - (ct[K] + 2.f*ct[K+1] + ct[K+2]))
        mkcoef(GY(0), gX[2]-gX[0], gc.x, g1c.x, gL,   gc.y, g1u.x, g1d.x, fs.x,
               ca0.x, caE.x, camx.x, capx.x, camy.x, capy.x, caS.x);
        mkcoef(GY(1), gX[3]-gX[1], gc.y, g1c.y, gc.x, gc.z, g1u.y, g1d.y, fs.y,
               ca0.y, caE.y, camx.y, capx.y, camy.y, capy.y, caS.y);
        mkcoef(GY(2), gX[4]-gX[2], gc.z, g1c.z, gc.y, gc.w, g1u.z, g1d.z, fs.z,
               ca0.z, caE.z, camx.z, capx.z, camy.z, capy.z, caS.z);
        mkcoef(GY(3), gX[5]-gX[3], gc.w, g1c.w, gc.z, gR,   g1u.w, g1d.w, fs.w,
               ca0.w, caE.w, camx.w, capx.w, camy.w, capy.w, caS.w);
        #undef GY
    }
    __syncthreads();   // gb/g1b reads done; r2 becomes hA/hB

    // ---- pass 3: init h buffers (h = h0 = fsrc); rows 0,27 are pads ----
    if (act) {
        *(float4*)&r2[(ci+1)*128 + w0]        = fs;   // hA
        *(float4*)&r2[3584 + (ci+1)*128 + w0] = fs;   // hB
    }
    __syncthreads();

    // ---- pass 4: 5 Jacobi iterations, all-immediate LDS addressing ----
    float* bU = &r2[ci*128 + w0];                      // row above (c-1)
    float* bM = &r2[(ci+1)*128 + ((w0 - 1) & 127)];    // left edge (circular)
    float* bP = &r2[(ci+1)*128 + ((w0 + 4) & 127)];    // right edge
    #pragma unroll
    for (int n = 0; n < 5; ++n) {
        const int co = (n & 1) ? 0 : 3584;   // cur buffer float offset
        const int po = 3584 - co;            // prv (receives h_{n+1})
        if (act) {
            float4 up = *(float4*)(bU + co);
            float4 hc = *(float4*)(bU + co + 128);
            float4 dn = *(float4*)(bU + co + 256);
            float4 h0 = *(float4*)(bU + po + 128);
            float  eL = bM[co];
            float  eR = bP[co];
            float4 nw;
            nw.x = ca0.x*h0.x - caE.x*hc.x + camx.x*eL   + capx.x*hc.y + camy.x*up.x + capy.x*dn.x + caS.x;
            nw.y = ca0.y*h0.y - caE.y*hc.y + camx.y*hc.x + capx.y*hc.z + camy.y*up.y + capy.y*dn.y + caS.y;
            nw.z = ca0.z*h0.z - caE.z*hc.z + camx.z*hc.y + capx.z*hc.w + camy.z*up.z + capy.z*dn.z + caS.z;
            nw.w = ca0.w*h0.w - caE.w*hc.w + camx.w*hc.z + capx.w*eR   + camy.w*up.w + capy.w*dn.w + caS.w;
            *(float4*)(bU + po + 128) = nw;
        }
        __syncthreads();
    }
    // final h is in hA = r2 (rows 1..26)

    // ---- pass 5: out = relu(bn(h)) on the 16 core channels ----
    if (tid < 512) {
        int i16 = tid & 15, w5 = ((tid >> 4) & 31) << 2;
        float4 v = *(float4*)&r2[(i16 + 6)*128 + w5];
        float sc = sm.obn[0][i16], bi = sm.obn[1][i16];
        size_t ob = (((size_t)b*HN + h)*WN + w5)*CN + (c0 + i16);
        stf(&out[ob],          fmaxf(v.x*sc + bi, 0.f));
        stf(&out[ob + CN],     fmaxf(v.y*sc + bi, 0.f));
        stf(&out[ob + 2*CN],   fmaxf(v.z*sc + bi, 0.f));
        stf(&out[ob + 3*CN],   fmaxf(v.w*sc + bi, 0.f));
    }
}

// Direct dispatch (dtype known host-side)
template <typename T>
__global__ __launch_bounds__(NTH, 4)
void diffusion_kernel(const T* __restrict__ s0,  const T* __restrict__ wg,  const T* __restrict__ wg1,
                      const T* __restrict__ g_gamma,  const T* __restrict__ g_beta,
                      const T* __restrict__ g_mean,   const T* __restrict__ g_var,
                      const T* __restrict__ g1_gamma, const T* __restrict__ g1_beta,
                      const T* __restrict__ g1_mean,  const T* __restrict__ g1_var,
                      const T* __restrict__ out_gamma, const T* __restrict__ out_beta,
                      const T* __restrict__ out_mean,  const T* __restrict__ out_var,
                      T* __restrict__ out)
{
    __shared__ SmemT sm;
    diffusion_body<T>(sm, s0, wg, wg1, g_gamma, g_beta, g_mean, g_var,
                      g1_gamma, g1_beta, g1_mean, g1_var,
                      out_gamma, out_beta, out_mean, out_var, out);
}

// Runtime-branched dispatch: ONE full-grid kernel, uniform branch on probe flag.
// Replaces the old probe + dual-dispatch (the ~175 µs dummy dispatch is gone).
__global__ __launch_bounds__(NTH, 4)
void diffusion_any(const void* s0, const void* wg, const void* wg1,
                   const void* a3, const void* a4, const void* a5, const void* a6,
                   const void* a7, const void* a8, const void* a9, const void* a10,
                   const void* a11, const void* a12, const void* a13, const void* a14,
                   void* out, const int* __restrict__ flag)
{
    __shared__ SmemT sm;
    if (*flag) {
        diffusion_body<__hip_bfloat16>(sm,
            (const __hip_bfloat16*)s0, (const __hip_bfloat16*)wg, (const __hip_bfloat16*)wg1,
            (const __hip_bfloat16*)a3, (const __hip_bfloat16*)a4, (const __hip_bfloat16*)a5, (const __hip_bfloat16*)a6,
            (const __hip_bfloat16*)a7, (const __hip_bfloat16*)a8, (const __hip_bfloat16*)a9, (const __hip_bfloat16*)a10,
            (const __hip_bfloat16*)a11, (const __hip_bfloat16*)a12, (const __hip_bfloat16*)a13, (const __hip_bfloat16*)a14,
            (__hip_bfloat16*)out);
    } else {
        diffusion_body<float>(sm,
            (const float*)s0, (const float*)wg, (const float*)wg1,
            (const float*)a3, (const float*)a4, (const float*)a5, (const float*)a6,
            (const float*)a7, (const float*)a8, (const float*)a9, (const float*)a10,
            (const float*)a11, (const float*)a12, (const float*)a13, (const float*)a14,
            (float*)out);
    }
}

extern "C" void kernel_launch(void* const* d_in, const int* in_sizes, int n_in,
                              void* d_out, int out_size, void* d_ws, size_t ws_size,
                              hipStream_t stream) {
    dim3 grid(BN * 16 * HN);   // 16384 blocks

    // Host-side dtype dispatch if in_sizes[0] is an unambiguous byte count.
    const long long nb    = (n_in > 0) ? (long long)in_sizes[0] : 0;
    const long long F32B  = (long long)BN * HN * WN * CN * 4;   // 134217728
    const long long BF16B = F32B / 2;                           //  67108864

    if (nb == F32B) {
        diffusion_kernel<float><<<grid, NTH, 0, stream>>>(
            (const float*)d_in[0], (const float*)d_in[1], (const float*)d_in[2],
            (const float*)d_in[3], (const float*)d_in[4], (const float*)d_in[5], (const float*)d_in[6],
            (const float*)d_in[7], (const float*)d_in[8], (const float*)d_in[9], (const float*)d_in[10],
            (const float*)d_in[11], (const float*)d_in[12], (const float*)d_in[13], (const float*)d_in[14],
            (float*)d_out);
    } else if (nb == BF16B) {
        diffusion_kernel<__hip_bfloat16><<<grid, NTH, 0, stream>>>(
            (const __hip_bfloat16*)d_in[0], (const __hip_bfloat16*)d_in[1], (const __hip_bfloat16*)d_in[2],
            (const __hip_bfloat16*)d_in[3], (const __hip_bfloat16*)d_in[4], (const __hip_bfloat16*)d_in[5], (const __hip_bfloat16*)d_in[6],
            (const __hip_bfloat16*)d_in[7], (const __hip_bfloat16*)d_in[8], (const __hip_bfloat16*)d_in[9], (const __hip_bfloat16*)d_in[10],
            (const __hip_bfloat16*)d_in[11], (const __hip_bfloat16*)d_in[12], (const __hip_bfloat16*)d_in[13], (const __hip_bfloat16*)d_in[14],
            (__hip_bfloat16*)d_out);
    } else if (ws_size >= 4) {
        // Probe once (1 block), then ONE runtime-branched full-grid dispatch.
        int* flag = (int*)d_ws;
        probe_kernel<<<1, 256, 0, stream>>>((const unsigned int*)d_in[0], flag);
        diffusion_any<<<grid, NTH, 0, stream>>>(
            d_in[0], d_in[1], d_in[2], d_in[3], d_in[4], d_in[5], d_in[6],
            d_in[7], d_in[8], d_in[9], d_in[10], d_in[11], d_in[12], d_in[13], d_in[14],
            d_out, flag);
    } else {
        diffusion_kernel<float><<<grid, NTH, 0, stream>>>(
            (const float*)d_in[0], (const float*)d_in[1], (const float*)d_in[2],
            (const float*)d_in[3], (const float*)d_in[4], (const float*)d_in[5], (const float*)d_in[6],
            (const float*)d_in[7], (const float*)d_in[8], (const float*)d_in[9], (const float*)d_in[10],
            (const float*)d_in[11], (const float*)d_in[12], (const float*)d_in[13], (const float*)d_in[14],
            (float*)d_out);
    }
}

// Round 7
// 533.263 us; speedup vs baseline: 1.2264x; 1.0130x over previous
//
#include <hip/hip_runtime.h>
#include <hip/hip_bf16.h>

#define BN 8
#define HN 128
#define WN 128
#define CN 256
#define DTC 0.2f
#define EPSV 1e-3f
#define NTH 1024

#define SJ 32      // staged channel rows (phys j: cj = c0-8+j)
#define SW 134     // w stride (u16): col0 & col129 zero pads, data at 1..128; rows 4B-aligned

// ---- dtype-generic helpers (compute stays f32) ----
__device__ __forceinline__ float ldf(const float* p)            { return *p; }
__device__ __forceinline__ float ldf(const __hip_bfloat16* p)   { return __bfloat162float(*p); }
__device__ __forceinline__ void stf(float* p, float v)          { *p = v; }
__device__ __forceinline__ void stf(__hip_bfloat16* p, float v) { *p = __float2bfloat16(v); }

// packed bf16 extraction from u32 (exact f32), little-endian: lo = even col
__device__ __forceinline__ float lo16(unsigned u){ return __uint_as_float(u << 16); }
__device__ __forceinline__ float hi16(unsigned u){ return __uint_as_float(u & 0xffff0000u); }

// stage 4 consecutive channels (one vector global load) into 4 LDS channel-rows
__device__ __forceinline__ void stage4(__hip_bfloat16* dp, const __hip_bfloat16* gp) {
    ushort4 v = *reinterpret_cast<const ushort4*>(gp);
    unsigned short* d = reinterpret_cast<unsigned short*>(dp);
    d[0] = v.x; d[SW] = v.y; d[2*SW] = v.z; d[3*SW] = v.w;
}
__device__ __forceinline__ void stage4(__hip_bfloat16* dp, const float* gp) {
    float4 v = *reinterpret_cast<const float4*>(gp);
    dp[0]    = __float2bfloat16(v.x);
    dp[SW]   = __float2bfloat16(v.y);
    dp[2*SW] = __float2bfloat16(v.z);
    dp[3*SW] = __float2bfloat16(v.w);
}

// ---- dtype probe: bf16 exponent band test on raw u32 words ----
__global__ void probe_kernel(const unsigned int* __restrict__ s0w, int* __restrict__ flag) {
    __shared__ int cnt;
    if (threadIdx.x == 0) cnt = 0;
    __syncthreads();
    int local = 0;
    for (int i = threadIdx.x; i < 4096; i += 256) {
        unsigned int e = (s0w[i] >> 7) & 0xFF;
        if (e >= 118 && e <= 130) local++;
    }
    atomicAdd(&cnt, local);
    __syncthreads();
    if (threadIdx.x == 0) *flag = (cnt > 2048) ? 1 : 0;   // 1 = bf16, 0 = f32
}

__device__ __forceinline__ void mkcoef(float gy, float gx, float gg, float g11,
                                       float gl, float gr, float g1u, float g1d, float fsrc,
                                       float& o0, float& oE, float& omx, float& opx,
                                       float& omy, float& opy, float& oS)
{
    // v_rcp_f32 (1 ulp) — tolerance 0.0625; validated r2-r4. Register-reducing vs IEEE div seq.
    float Dx = __builtin_amdgcn_rcpf(fmaf(gy*gy, 0.25f, 1.f));
    float Dy = __builtin_amdgcn_rcpf(fmaf(gx*gx, 0.25f, 1.f));
    float ux = 0.5f * (gl - gr);
    float vy = 0.5f * (g1u - g1d);
    float Ax = gg*DTC, Ay = g11*DTC;
    float Bx = Dx*DTC, By = Dy*DTC;
    float Ev = (ux + vy)*DTC;
    float s2 = 2.f*(Bx + By);
    float Dv = __builtin_amdgcn_rcpf(1.f + s2);
    o0  = Dv*(1.f - s2);
    oE  = 2.f*Dv*Ev;
    omx = Dv*(2.f*Bx - Ax);
    opx = Dv*(2.f*Bx + Ax);
    omy = Dv*(2.f*By - Ay);
    opy = Dv*(2.f*By + Ay);
    oS  = Dv*(2.f*DTC)*fsrc;
}

template <typename T>
__global__ __launch_bounds__(NTH, 4)   // lb4: proven-good codegen (r0/r6); body must stay <=32 VGPR for 2 blocks/CU
void diffusion_kernel(const T* __restrict__ s0,  const T* __restrict__ wg,  const T* __restrict__ wg1,
                      const T* __restrict__ g_gamma,  const T* __restrict__ g_beta,
                      const T* __restrict__ g_mean,   const T* __restrict__ g_var,
                      const T* __restrict__ g1_gamma, const T* __restrict__ g1_beta,
                      const T* __restrict__ g1_mean,  const T* __restrict__ g1_var,
                      const T* __restrict__ out_gamma, const T* __restrict__ out_beta,
                      const T* __restrict__ out_mean,  const T* __restrict__ out_var,
                      T* __restrict__ out,
                      const int* __restrict__ flag, int want)
{
    if (flag && *flag != want) return;   // dtype dispatch (dummy instance exits in ~9 us)

    __shared__ __hip_bfloat16 s0s[3][SJ][SW];      // 25728 B
    __shared__ float wgt[2][9][SJ];                //  2304 B
    __shared__ float bnp[4][SJ];                   //   512 B
    __shared__ float obn[2][16];                   //   128 B
    __shared__ __align__(16) float r2[2*28*128];   // 28672 B : gb/g1b then hA/hB
    // total 57344 B -> 2 blocks/CU (with VGPR<=32)

    const int tid = threadIdx.x;
    const int bid = blockIdx.x;
    const int h     = bid & 127;
    const int bc    = bid >> 7;
    const int chunk = bc & 15;
    const int b     = bc >> 4;
    const int c0    = chunk << 4;

    const int   rT   = (h > 0)   ? h - 1 : 1;      // sobel reflect rows
    const int   rB   = (h < 127) ? h + 1 : 126;
    const float topf = (h > 0)   ? 1.f : 0.f;      // conv zero-pad flags
    const float botf = (h < 127) ? 1.f : 0.f;

    // ---- stage s0: 3 rows x 32 ch x 128 w; 4-channel vector loads (3072 total, 3/thread) ----
    {
        const size_t base = (size_t)b * HN * WN * CN;
        #pragma unroll
        for (int k = 0; k < 3; ++k) {
            int e  = tid + k * NTH;                // < 3072
            int j4 = e & 7;                        // 4-channel group
            int w  = (e >> 3) & 127;
            int r  = e >> 10;                      // 0..2
            int row = (r == 0) ? rT : ((r == 1) ? h : rB);
            int cj  = (c0 - 8 + (j4 << 2)) & 255;  // 4-aligned group never straddles the wrap
            stage4(&s0s[r][j4 << 2][w + 1], &s0[base + ((size_t)row * WN + w) * CN + cj]);
        }
    }
    if (tid < 192) {                               // zero pad columns (conv SAME)
        int r = tid >> 6, j = (tid >> 1) & 31, cp = (tid & 1) ? 129 : 0;
        s0s[r][j][cp] = __float2bfloat16(0.f);
    }
    if (tid < 288) {                               // weights, H-pad folded in
        int t9 = tid >> 5, j = tid & 31;
        int cj = (c0 - 8 + j) & 255;
        float rf = (t9 < 3) ? topf : ((t9 >= 6) ? botf : 1.f);
        wgt[0][t9][j] = ldf(&wg [t9*CN + cj]) * rf;
        wgt[1][t9][j] = ldf(&wg1[t9*CN + cj]) * rf;
    }
    if (tid < 32) {                                // folded BN params
        int cj = (c0 - 8 + tid) & 255;
        float s  = ldf(&g_gamma[cj])  * rsqrtf(ldf(&g_var[cj])  + EPSV);
        bnp[0][tid] = s;
        bnp[1][tid] = ldf(&g_beta[cj])  - ldf(&g_mean[cj])  * s;
        float s1 = ldf(&g1_gamma[cj]) * rsqrtf(ldf(&g1_var[cj]) + EPSV);
        bnp[2][tid] = s1;
        bnp[3][tid] = ldf(&g1_beta[cj]) - ldf(&g1_mean[cj]) * s1;
    }
    if (tid < 16) {
        int c = c0 + tid;
        float s = ldf(&out_gamma[c]) * rsqrtf(ldf(&out_var[c]) + EPSV);
        obn[0][tid] = s;
        obn[1][tid] = ldf(&out_beta[c]) - ldf(&out_mean[c]) * s;
    }
    __syncthreads();

    float* gb  = r2;            // [28][128]
    float* g1b = r2 + 3584;

    // ---- pass 1: depthwise conv + BN + relu; aligned u32-pair LDS reads + unpack ----
    if (tid < 896) {            // 28 rows x 32 quads
        int wq = tid & 31, l = tid >> 5, j = l + 2, w0 = wq << 2;
        float col[3][6];
        #pragma unroll
        for (int r = 0; r < 3; ++r) {
            const unsigned* p = reinterpret_cast<const unsigned*>(&s0s[r][j][w0]);  // 4B-aligned
            unsigned d0 = p[0], d1 = p[1], d2 = p[2];
            col[r][0] = lo16(d0); col[r][1] = hi16(d0);
            col[r][2] = lo16(d1); col[r][3] = hi16(d1);
            col[r][4] = lo16(d2); col[r][5] = hi16(d2);
        }
        float gvk[4], g1vk[4];
        #pragma unroll
        for (int k = 0; k < 4; ++k) {
            float a = 0.f, a1 = 0.f;
            #pragma unroll
            for (int r = 0; r < 3; ++r)
                #pragma unroll
                for (int dx = 0; dx < 3; ++dx) {
                    float v = col[r][k + dx];
                    a  = fmaf(v, wgt[0][r*3+dx][j], a);
                    a1 = fmaf(v, wgt[1][r*3+dx][j], a1);
                }
            a  = fmaf(a,  bnp[0][j], bnp[1][j]);
            a1 = fmaf(a1, bnp[2][j], bnp[3][j]);
            gvk[k]  = fmaxf(a , 0.f);
            g1vk[k] = fmaxf(a1, 0.f);
        }
        *(float4*)&gb [l*128 + w0] = make_float4(gvk[0],  gvk[1],  gvk[2],  gvk[3]);
        *(float4*)&g1b[l*128 + w0] = make_float4(g1vk[0], g1vk[1], g1vk[2], g1vk[3]);
    }
    __syncthreads();

    // ---- pass 2: per-cell coefficients; aligned reads + cndmask reflect (r1-validated) ----
    float4 ca0, caE, camx, capx, camy, capy, caS, fs;
    const int wq = tid & 31, ci = tid >> 5, w0 = wq << 2;  // ci in 0..25 for active
    const bool act = (tid < 832);                          // 26 rows x 32 quads
    if (act) {
        int li = ci + 1, j = ci + 3;
        // phys cols w0..w0+5 = logical w0-1..w0+4 (the exact sobel window)
        float col[3][6];
        #pragma unroll
        for (int r = 0; r < 3; ++r) {
            const unsigned* p = reinterpret_cast<const unsigned*>(&s0s[r][j][w0]);
            unsigned d0 = p[0], d1 = p[1], d2 = p[2];
            col[r][0] = lo16(d0); col[r][1] = hi16(d0);
            col[r][2] = lo16(d1); col[r][3] = hi16(d1);
            col[r][4] = lo16(d2); col[r][5] = hi16(d2);
        }
        // reflect overrides at W edges (pads hold conv zeros; sobel needs reflect)
        #pragma unroll
        for (int r = 0; r < 3; ++r) {
            col[r][0] = (wq == 0)  ? col[r][2] : col[r][0];
            col[r][5] = (wq == 31) ? col[r][3] : col[r][5];
        }
        float gX[6], dY[6];
        #pragma unroll
        for (int c = 0; c < 6; ++c) {
            gX[c] = col[0][c] + 2.f*col[1][c] + col[2][c];
            dY[c] = col[2][c] - col[0][c];
        }
        float4 gc  = *(float4*)&gb [li*128 + w0];
        float  gL  = gb[li*128 + ((w0 - 1) & 127)];
        float  gR  = gb[li*128 + ((w0 + 4) & 127)];
        float4 g1c = *(float4*)&g1b[li*128 + w0];
        float4 g1u = *(float4*)&g1b[(li-1)*128 + w0];
        float4 g1d = *(float4*)&g1b[(li+1)*128 + w0];
        fs = make_float4(col[1][1], col[1][2], col[1][3], col[1][4]);

        #define GYV(K) (dY[K] + 2.f*dY[K+1] + dY[K+2])
        mkcoef(GYV(0), gX[2]-gX[0], gc.x, g1c.x, gL,   gc.y, g1u.x, g1d.x, fs.x,
               ca0.x, caE.x, camx.x, capx.x, camy.x, capy.x, caS.x);
        mkcoef(GYV(1), gX[3]-gX[1], gc.y, g1c.y, gc.x, gc.z, g1u.y, g1d.y, fs.y,
               ca0.y, caE.y, camx.y, capx.y, camy.y, capy.y, caS.y);
        mkcoef(GYV(2), gX[4]-gX[2], gc.z, g1c.z, gc.y, gc.w, g1u.z, g1d.z, fs.z,
               ca0.z, caE.z, camx.z, capx.z, camy.z, capy.z, caS.z);
        mkcoef(GYV(3), gX[5]-gX[3], gc.w, g1c.w, gc.z, gR,   g1u.w, g1d.w, fs.w,
               ca0.w, caE.w, camx.w, capx.w, camy.w, capy.w, caS.w);
        #undef GYV
    }
    __syncthreads();   // gb/g1b reads done; r2 becomes hA/hB

    // ---- pass 3: init h buffers (h = h0 = fsrc); rows 0,27 are pads ----
    if (act) {
        *(float4*)&r2[(ci+1)*128 + w0]        = fs;   // hA
        *(float4*)&r2[3584 + (ci+1)*128 + w0] = fs;   // hB
    }
    __syncthreads();

    // ---- pass 4: 5 Jacobi iterations, all-immediate LDS addressing ----
    float* bU = &r2[ci*128 + w0];                      // row above (c-1)
    float* bM = &r2[(ci+1)*128 + ((w0 - 1) & 127)];    // left edge (circular)
    float* bP = &r2[(ci+1)*128 + ((w0 + 4) & 127)];    // right edge
    #pragma unroll
    for (int n = 0; n < 5; ++n) {
        const int co = (n & 1) ? 0 : 3584;   // cur buffer float offset
        const int po = 3584 - co;            // prv (receives h_{n+1})
        if (act) {
            float4 up = *(float4*)(bU + co);
            float4 hc = *(float4*)(bU + co + 128);
            float4 dn = *(float4*)(bU + co + 256);
            float4 h0 = *(float4*)(bU + po + 128);
            float  eL = bM[co];
            float  eR = bP[co];
            float4 nw;
            nw.x = ca0.x*h0.x - caE.x*hc.x + camx.x*eL   + capx.x*hc.y + camy.x*up.x + capy.x*dn.x + caS.x;
            nw.y = ca0.y*h0.y - caE.y*hc.y + camx.y*hc.x + capx.y*hc.z + camy.y*up.y + capy.y*dn.y + caS.y;
            nw.z = ca0.z*h0.z - caE.z*hc.z + camx.z*hc.y + capx.z*hc.w + camy.z*up.z + capy.z*dn.z + caS.z;
            nw.w = ca0.w*h0.w - caE.w*hc.w + camx.w*hc.z + capx.w*eR   + camy.w*up.w + capy.w*dn.w + caS.w;
            *(float4*)(bU + po + 128) = nw;
        }
        __syncthreads();
    }
    // final h is in hA = r2 (rows 1..26)

    // ---- pass 5: out = relu(bn(h)) on the 16 core channels ----
    if (tid < 512) {
        int i16 = tid & 15, w5 = ((tid >> 4) & 31) << 2;
        float4 v = *(float4*)&r2[(i16 + 6)*128 + w5];
        float sc = obn[0][i16], bi = obn[1][i16];
        size_t ob = (((size_t)b*HN + h)*WN + w5)*CN + (c0 + i16);
        stf(&out[ob],          fmaxf(fmaf(v.x, sc, bi), 0.f));
        stf(&out[ob + CN],     fmaxf(fmaf(v.y, sc, bi), 0.f));
        stf(&out[ob + 2*CN],   fmaxf(fmaf(v.z, sc, bi), 0.f));
        stf(&out[ob + 3*CN],   fmaxf(fmaf(v.w, sc, bi), 0.f));
    }
}

extern "C" void kernel_launch(void* const* d_in, const int* in_sizes, int n_in,
                              void* d_out, int out_size, void* d_ws, size_t ws_size,
                              hipStream_t stream) {
    dim3 grid(BN * 16 * HN);   // 16384 blocks

    // Host-side dtype dispatch if in_sizes[0] happens to be an unambiguous byte count.
    const long long nb    = (n_in > 0) ? (long long)in_sizes[0] : 0;
    const long long F32B  = (long long)BN * HN * WN * CN * 4;   // 134217728
    const long long BF16B = F32B / 2;                           //  67108864

    if (nb == F32B) {
        diffusion_kernel<float><<<grid, NTH, 0, stream>>>(
            (const float*)d_in[0], (const float*)d_in[1], (const float*)d_in[2],
            (const float*)d_in[3], (const float*)d_in[4], (const float*)d_in[5], (const float*)d_in[6],
            (const float*)d_in[7], (const float*)d_in[8], (const float*)d_in[9], (const float*)d_in[10],
            (const float*)d_in[11], (const float*)d_in[12], (const float*)d_in[13], (const float*)d_in[14],
            (float*)d_out, nullptr, 0);
    } else if (nb == BF16B) {
        diffusion_kernel<__hip_bfloat16><<<grid, NTH, 0, stream>>>(
            (const __hip_bfloat16*)d_in[0], (const __hip_bfloat16*)d_in[1], (const __hip_bfloat16*)d_in[2],
            (const __hip_bfloat16*)d_in[3], (const __hip_bfloat16*)d_in[4], (const __hip_bfloat16*)d_in[5], (const __hip_bfloat16*)d_in[6],
            (const __hip_bfloat16*)d_in[7], (const __hip_bfloat16*)d_in[8], (const __hip_bfloat16*)d_in[9], (const __hip_bfloat16*)d_in[10],
            (const __hip_bfloat16*)d_in[11], (const __hip_bfloat16*)d_in[12], (const __hip_bfloat16*)d_in[13], (const __hip_bfloat16*)d_in[14],
            (__hip_bfloat16*)d_out, nullptr, 0);
    } else if (ws_size >= 4) {
        // Probe + dual templated dispatch (dummy instance exits early, ~9 us — r6 measured)
        int* flag = (int*)d_ws;
        probe_kernel<<<1, 256, 0, stream>>>((const unsigned int*)d_in[0], flag);

        diffusion_kernel<float><<<grid, NTH, 0, stream>>>(
            (const float*)d_in[0], (const float*)d_in[1], (const float*)d_in[2],
            (const float*)d_in[3], (const float*)d_in[4], (const float*)d_in[5], (const float*)d_in[6],
            (const float*)d_in[7], (const float*)d_in[8], (const float*)d_in[9], (const float*)d_in[10],
            (const float*)d_in[11], (const float*)d_in[12], (const float*)d_in[13], (const float*)d_in[14],
            (float*)d_out, flag, 0);

        diffusion_kernel<__hip_bfloat16><<<grid, NTH, 0, stream>>>(
            (const __hip_bfloat16*)d_in[0], (const __hip_bfloat16*)d_in[1], (const __hip_bfloat16*)d_in[2],
            (const __hip_bfloat16*)d_in[3], (const __hip_bfloat16*)d_in[4], (const __hip_bfloat16*)d_in[5], (const __hip_bfloat16*)d_in[6],
            (const __hip_bfloat16*)d_in[7], (const __hip_bfloat16*)d_in[8], (const __hip_bfloat16*)d_in[9], (const __hip_bfloat16*)d_in[10],
            (const __hip_bfloat16*)d_in[11], (const __hip_bfloat16*)d_in[12], (const __hip_bfloat16*)d_in[13], (const __hip_bfloat16*)d_in[14],
            (__hip_bfloat16*)d_out, flag, 1);
    } else {
        diffusion_kernel<float><<<grid, NTH, 0, stream>>>(
            (const float*)d_in[0], (const float*)d_in[1], (const float*)d_in[2],
            (const float*)d_in[3], (const float*)d_in[4], (const float*)d_in[5], (const float*)d_in[6],
            (const float*)d_in[7], (const float*)d_in[8], (const float*)d_in[9], (const float*)d_in[10],
            (const float*)d_in[11], (const float*)d_in[12], (const float*)d_in[13], (const float*)d_in[14],
            (float*)d_out, nullptr, 0);
    }
}

// Round 8
// 485.543 us; speedup vs baseline: 1.3470x; 1.0983x over previous
//
#include <hip/hip_runtime.h>
#include <hip/hip_bf16.h>

#define BN 8
#define HN 128
#define WN 128
#define CN 256
#define DTC 0.2f
#define EPSV 1e-3f
#define NTH 1024

#define SJ 32      // staged channel rows (phys j: cj = c0-8+j)
#define SW 134     // w stride (u16): col0 & col129 zero pads, data at 1..128; rows 4B-aligned

// ---- dtype-generic helpers (compute stays f32) ----
__device__ __forceinline__ float ldf(const float* p)            { return *p; }
__device__ __forceinline__ float ldf(const __hip_bfloat16* p)   { return __bfloat162float(*p); }
__device__ __forceinline__ void stf(float* p, float v)          { *p = v; }
__device__ __forceinline__ void stf(__hip_bfloat16* p, float v) { *p = __float2bfloat16(v); }

// packed bf16 extraction from u32 (exact f32), little-endian: lo = even col
__device__ __forceinline__ float lo16(unsigned u){ return __uint_as_float(u << 16); }
__device__ __forceinline__ float hi16(unsigned u){ return __uint_as_float(u & 0xffff0000u); }

// stage 4 consecutive channels (one vector global load) into 4 LDS channel-rows
__device__ __forceinline__ void stage4(__hip_bfloat16* dp, const __hip_bfloat16* gp) {
    ushort4 v = *reinterpret_cast<const ushort4*>(gp);
    unsigned short* d = reinterpret_cast<unsigned short*>(dp);
    d[0] = v.x; d[SW] = v.y; d[2*SW] = v.z; d[3*SW] = v.w;
}
__device__ __forceinline__ void stage4(__hip_bfloat16* dp, const float* gp) {
    float4 v = *reinterpret_cast<const float4*>(gp);
    dp[0]    = __float2bfloat16(v.x);
    dp[SW]   = __float2bfloat16(v.y);
    dp[2*SW] = __float2bfloat16(v.z);
    dp[3*SW] = __float2bfloat16(v.w);
}

// ---- dtype probe: bf16 exponent band test on raw u32 words ----
__global__ void probe_kernel(const unsigned int* __restrict__ s0w, int* __restrict__ flag) {
    __shared__ int cnt;
    if (threadIdx.x == 0) cnt = 0;
    __syncthreads();
    int local = 0;
    for (int i = threadIdx.x; i < 4096; i += 256) {
        unsigned int e = (s0w[i] >> 7) & 0xFF;
        if (e >= 118 && e <= 130) local++;
    }
    atomicAdd(&cnt, local);
    __syncthreads();
    if (threadIdx.x == 0) *flag = (cnt > 2048) ? 1 : 0;   // 1 = bf16, 0 = f32
}

__device__ __forceinline__ void mkcoef(float gy, float gx, float gg, float g11,
                                       float gl, float gr, float g1u, float g1d, float fsrc,
                                       float& o0, float& oE, float& omx, float& opx,
                                       float& omy, float& opy, float& oS)
{
    // v_rcp_f32 (1 ulp) — tolerance 0.0625; validated r2-r4/r7.
    float Dx = __builtin_amdgcn_rcpf(fmaf(gy*gy, 0.25f, 1.f));
    float Dy = __builtin_amdgcn_rcpf(fmaf(gx*gx, 0.25f, 1.f));
    float ux = 0.5f * (gl - gr);
    float vy = 0.5f * (g1u - g1d);
    float Ax = gg*DTC, Ay = g11*DTC;
    float Bx = Dx*DTC, By = Dy*DTC;
    float Ev = (ux + vy)*DTC;
    float s2 = 2.f*(Bx + By);
    float Dv = __builtin_amdgcn_rcpf(1.f + s2);
    o0  = Dv*(1.f - s2);
    oE  = 2.f*Dv*Ev;
    omx = Dv*(2.f*Bx - Ax);
    opx = Dv*(2.f*Bx + Ax);
    omy = Dv*(2.f*By - Ay);
    opy = Dv*(2.f*By + Ay);
    oS  = Dv*(2.f*DTC)*fsrc;
}

template <typename T>
__global__ __launch_bounds__(NTH, 4)   // lb4: proven codegen; body targets <=32 VGPR for 2 blocks/CU
void diffusion_kernel(const T* __restrict__ s0,  const T* __restrict__ wg,  const T* __restrict__ wg1,
                      const T* __restrict__ g_gamma,  const T* __restrict__ g_beta,
                      const T* __restrict__ g_mean,   const T* __restrict__ g_var,
                      const T* __restrict__ g1_gamma, const T* __restrict__ g1_beta,
                      const T* __restrict__ g1_mean,  const T* __restrict__ g1_var,
                      const T* __restrict__ out_gamma, const T* __restrict__ out_beta,
                      const T* __restrict__ out_mean,  const T* __restrict__ out_var,
                      T* __restrict__ out,
                      const int* __restrict__ flag, int want)
{
    if (flag && *flag != want) return;   // dtype dispatch (dummy instance exits in ~9 us)

    __shared__ __hip_bfloat16 s0s[3][SJ][SW];      // 25728 B
    __shared__ float wgt[2][9][SJ];                //  2304 B
    __shared__ float bnp[4][SJ];                   //   512 B
    __shared__ float obn[2][16];                   //   128 B
    __shared__ __align__(16) float r2[2*28*128];   // 28672 B : gb/g1b then hA/hB
    // total 57344 B -> 2 blocks/CU (with VGPR<=32)

    const int tid = threadIdx.x;
    const int bid = blockIdx.x;
    const int h     = bid & 127;
    const int bc    = bid >> 7;
    const int chunk = bc & 15;
    const int b     = bc >> 4;
    const int c0    = chunk << 4;

    const int   rT   = (h > 0)   ? h - 1 : 1;      // sobel reflect rows
    const int   rB   = (h < 127) ? h + 1 : 126;
    const float topf = (h > 0)   ? 1.f : 0.f;      // conv zero-pad flags
    const float botf = (h < 127) ? 1.f : 0.f;

    // ---- stage s0: 3 rows x 32 ch x 128 w; 4-channel vector loads (3072 total, 3/thread) ----
    {
        const size_t base = (size_t)b * HN * WN * CN;
        #pragma unroll
        for (int k = 0; k < 3; ++k) {
            int e  = tid + k * NTH;                // < 3072
            int j4 = e & 7;                        // 4-channel group
            int w  = (e >> 3) & 127;
            int r  = e >> 10;                      // 0..2
            int row = (r == 0) ? rT : ((r == 1) ? h : rB);
            int cj  = (c0 - 8 + (j4 << 2)) & 255;  // 4-aligned group never straddles the wrap
            stage4(&s0s[r][j4 << 2][w + 1], &s0[base + ((size_t)row * WN + w) * CN + cj]);
        }
    }
    if (tid < 192) {                               // zero pad columns (conv SAME)
        int r = tid >> 6, j = (tid >> 1) & 31, cp = (tid & 1) ? 129 : 0;
        s0s[r][j][cp] = __float2bfloat16(0.f);
    }
    if (tid < 288) {                               // weights, H-pad folded in
        int t9 = tid >> 5, j = tid & 31;
        int cj = (c0 - 8 + j) & 255;
        float rf = (t9 < 3) ? topf : ((t9 >= 6) ? botf : 1.f);
        wgt[0][t9][j] = ldf(&wg [t9*CN + cj]) * rf;
        wgt[1][t9][j] = ldf(&wg1[t9*CN + cj]) * rf;
    }
    if (tid < 32) {                                // folded BN params
        int cj = (c0 - 8 + tid) & 255;
        float s  = ldf(&g_gamma[cj])  * rsqrtf(ldf(&g_var[cj])  + EPSV);
        bnp[0][tid] = s;
        bnp[1][tid] = ldf(&g_beta[cj])  - ldf(&g_mean[cj])  * s;
        float s1 = ldf(&g1_gamma[cj]) * rsqrtf(ldf(&g1_var[cj]) + EPSV);
        bnp[2][tid] = s1;
        bnp[3][tid] = ldf(&g1_beta[cj]) - ldf(&g1_mean[cj]) * s1;
    }
    if (tid < 16) {
        int c = c0 + tid;
        float s = ldf(&out_gamma[c]) * rsqrtf(ldf(&out_var[c]) + EPSV);
        obn[0][tid] = s;
        obn[1][tid] = ldf(&out_beta[c]) - ldf(&out_mean[c]) * s;
    }
    __syncthreads();   // B1

    float* gb  = r2;            // [28][128]
    float* g1b = r2 + 3584;

    // ---- pass 1: depthwise conv + BN + relu; aligned u32-pair LDS reads + unpack ----
    if (tid < 896) {            // 28 rows x 32 quads
        int wq = tid & 31, l = tid >> 5, j = l + 2, w0 = wq << 2;
        float col[3][6];
        #pragma unroll
        for (int r = 0; r < 3; ++r) {
            const unsigned* p = reinterpret_cast<const unsigned*>(&s0s[r][j][w0]);  // 4B-aligned
            unsigned d0 = p[0], d1 = p[1], d2 = p[2];
            col[r][0] = lo16(d0); col[r][1] = hi16(d0);
            col[r][2] = lo16(d1); col[r][3] = hi16(d1);
            col[r][4] = lo16(d2); col[r][5] = hi16(d2);
        }
        float gvk[4], g1vk[4];
        #pragma unroll
        for (int k = 0; k < 4; ++k) {
            float a = 0.f, a1 = 0.f;
            #pragma unroll
            for (int r = 0; r < 3; ++r)
                #pragma unroll
                for (int dx = 0; dx < 3; ++dx) {
                    float v = col[r][k + dx];
                    a  = fmaf(v, wgt[0][r*3+dx][j], a);
                    a1 = fmaf(v, wgt[1][r*3+dx][j], a1);
                }
            a  = fmaf(a,  bnp[0][j], bnp[1][j]);
            a1 = fmaf(a1, bnp[2][j], bnp[3][j]);
            gvk[k]  = fmaxf(a , 0.f);
            g1vk[k] = fmaxf(a1, 0.f);
        }
        *(float4*)&gb [l*128 + w0] = make_float4(gvk[0],  gvk[1],  gvk[2],  gvk[3]);
        *(float4*)&g1b[l*128 + w0] = make_float4(g1vk[0], g1vk[1], g1vk[2], g1vk[3]);
    }
    __syncthreads();   // B2

    // ---- thread geometry for pass 2 + Jacobi ----
    const int wq = tid & 31, ci = tid >> 5, w0 = wq << 2;  // ci in 0..25 for active
    const bool act = (tid < 832);                          // 26 rows x 32 quads (13 full waves)
    const int lane = tid & 63;
    const int sL = (lane & 32) | ((lane + 31) & 31);       // left rotate within half-wave (W wrap)
    const int sR = (lane & 32) | ((lane + 1)  & 31);

    // ---- pass 2: per-cell coefficients; scalar neighbor reads replaced by shuffles ----
    float4 ca0, caE, camx, capx, camy, capy, caS, fs;
    if (act) {
        int li = ci + 1, j = ci + 3;
        // phys cols w0..w0+5 = logical w0-1..w0+4 (the exact sobel window)
        float col[3][6];
        #pragma unroll
        for (int r = 0; r < 3; ++r) {
            const unsigned* p = reinterpret_cast<const unsigned*>(&s0s[r][j][w0]);
            unsigned d0 = p[0], d1 = p[1], d2 = p[2];
            col[r][0] = lo16(d0); col[r][1] = hi16(d0);
            col[r][2] = lo16(d1); col[r][3] = hi16(d1);
            col[r][4] = lo16(d2); col[r][5] = hi16(d2);
        }
        fs = make_float4(col[1][1], col[1][2], col[1][3], col[1][4]);
        // reflect overrides at W edges (pads hold conv zeros; sobel needs reflect)
        #pragma unroll
        for (int r = 0; r < 3; ++r) {
            col[r][0] = (wq == 0)  ? col[r][2] : col[r][0];
            col[r][5] = (wq == 31) ? col[r][3] : col[r][5];
        }
        float gX[6], dY[6];
        #pragma unroll
        for (int c = 0; c < 6; ++c) {
            gX[c] = col[0][c] + 2.f*col[1][c] + col[2][c];
            dY[c] = col[2][c] - col[0][c];
        }
        float4 gc  = *(float4*)&gb [li*128 + w0];
        float  gL  = __shfl(gc.w, sL);    // was 8-way-conflicted b32 read
        float  gR  = __shfl(gc.x, sR);
        float4 g1c = *(float4*)&g1b[li*128 + w0];
        float4 g1u = *(float4*)&g1b[(li-1)*128 + w0];
        float4 g1d = *(float4*)&g1b[(li+1)*128 + w0];

        #define GYV(K) (dY[K] + 2.f*dY[K+1] + dY[K+2])
        mkcoef(GYV(0), gX[2]-gX[0], gc.x, g1c.x, gL,   gc.y, g1u.x, g1d.x, fs.x,
               ca0.x, caE.x, camx.x, capx.x, camy.x, capy.x, caS.x);
        mkcoef(GYV(1), gX[3]-gX[1], gc.y, g1c.y, gc.x, gc.z, g1u.y, g1d.y, fs.y,
               ca0.y, caE.y, camx.y, capx.y, camy.y, capy.y, caS.y);
        mkcoef(GYV(2), gX[4]-gX[2], gc.z, g1c.z, gc.y, gc.w, g1u.z, g1d.z, fs.z,
               ca0.z, caE.z, camx.z, capx.z, camy.z, capy.z, caS.z);
        mkcoef(GYV(3), gX[5]-gX[3], gc.w, g1c.w, gc.z, gR,   g1u.w, g1d.w, fs.w,
               ca0.w, caE.w, camx.w, capx.w, camy.w, capy.w, caS.w);
        #undef GYV
    }
    __syncthreads();   // B3: gb/g1b reads done; r2 becomes hA/hB

    // ---- Jacobi: 5 iterations, unrolled. h-row halos (rows 0,27) are never needed:
    //      5 iters propagate <=5 rows; outputs (rows 6..21) see only rows 1..26. ----
    float* hA = r2;            // [28][128]
    float* hB = r2 + 3584;
    const int rb = ci*128 + w0;          // row-above base; own row at rb+128

    auto JSTEP = [&](const float4& h0, const float4& hc, float eL, float eR,
                     const float4& up, const float4& dn) {
        float4 nw;
        nw.x = ca0.x*h0.x - caE.x*hc.x + camx.x*eL   + capx.x*hc.y + camy.x*up.x + capy.x*dn.x + caS.x;
        nw.y = ca0.y*h0.y - caE.y*hc.y + camx.y*hc.x + capx.y*hc.z + camy.y*up.y + capy.y*dn.y + caS.y;
        nw.z = ca0.z*h0.z - caE.z*hc.z + camx.z*hc.y + capx.z*hc.w + camy.z*up.z + capy.z*dn.z + caS.z;
        nw.w = ca0.w*h0.w - caE.w*hc.w + camx.w*hc.z + capx.w*eR   + camy.w*up.w + capy.w*dn.w + caS.w;
        return nw;
    };

    // iter 0: all operands are fsrc-field values — from registers + staged s0 mid-row.
    if (act) {
        int j = ci + 3;
        const unsigned* pu = reinterpret_cast<const unsigned*>(&s0s[1][j-1][w0]);
        unsigned u0 = pu[0], u1 = pu[1], u2 = pu[2];
        float4 up0 = make_float4(hi16(u0), lo16(u1), hi16(u1), lo16(u2));
        const unsigned* pd = reinterpret_cast<const unsigned*>(&s0s[1][j+1][w0]);
        unsigned d0 = pd[0], d1 = pd[1], d2 = pd[2];
        float4 dn0 = make_float4(hi16(d0), lo16(d1), hi16(d1), lo16(d2));
        float eL0 = __shfl(fs.w, sL);
        float eR0 = __shfl(fs.x, sR);
        float4 nw = JSTEP(fs, fs, eL0, eR0, up0, dn0);   // h0 = hc = fs
        *(float4*)&hA[rb + 128] = nw;                    // h1 -> hA
    }
    __syncthreads();   // B4

    // iter 1: cur=hA, h0 = fs (register), write hB
    if (act) {
        float4 up = *(float4*)&hA[rb];
        float4 hc = *(float4*)&hA[rb + 128];
        float4 dn = *(float4*)&hA[rb + 256];
        float eL = __shfl(hc.w, sL);
        float eR = __shfl(hc.x, sR);
        float4 nw = JSTEP(fs, hc, eL, eR, up, dn);       // h2 -> hB
        *(float4*)&hB[rb + 128] = nw;
    }
    __syncthreads();   // B5

    // iter 2: cur=hB, h0 = h1 (hA own cells, thread-private RMW), write hA
    if (act) {
        float4 up = *(float4*)&hB[rb];
        float4 hc = *(float4*)&hB[rb + 128];
        float4 dn = *(float4*)&hB[rb + 256];
        float4 h0 = *(float4*)&hA[rb + 128];
        float eL = __shfl(hc.w, sL);
        float eR = __shfl(hc.x, sR);
        float4 nw = JSTEP(h0, hc, eL, eR, up, dn);       // h3 -> hA
        *(float4*)&hA[rb + 128] = nw;
    }
    __syncthreads();   // B6

    // iter 3: cur=hA, h0 = h2 (hB own), write hB
    if (act) {
        float4 up = *(float4*)&hA[rb];
        float4 hc = *(float4*)&hA[rb + 128];
        float4 dn = *(float4*)&hA[rb + 256];
        float4 h0 = *(float4*)&hB[rb + 128];
        float eL = __shfl(hc.w, sL);
        float eR = __shfl(hc.x, sR);
        float4 nw = JSTEP(h0, hc, eL, eR, up, dn);       // h4 -> hB
        *(float4*)&hB[rb + 128] = nw;
    }
    __syncthreads();   // B7

    // iter 4: cur=hB, h0 = h3 (hA own), write hA (final h5)
    if (act) {
        float4 up = *(float4*)&hB[rb];
        float4 hc = *(float4*)&hB[rb + 128];
        float4 dn = *(float4*)&hB[rb + 256];
        float4 h0 = *(float4*)&hA[rb + 128];
        float eL = __shfl(hc.w, sL);
        float eR = __shfl(hc.x, sR);
        float4 nw = JSTEP(h0, hc, eL, eR, up, dn);       // h5 -> hA
        *(float4*)&hA[rb + 128] = nw;
    }
    __syncthreads();   // B8

    // ---- pass 5: out = relu(bn(h)) on the 16 core channels (hA rows 6..21) ----
    if (tid < 512) {
        int i16 = tid & 15, w5 = ((tid >> 4) & 31) << 2;
        float4 v = *(float4*)&hA[(i16 + 6)*128 + w5];
        float sc = obn[0][i16], bi = obn[1][i16];
        size_t ob = (((size_t)b*HN + h)*WN + w5)*CN + (c0 + i16);
        stf(&out[ob],          fmaxf(fmaf(v.x, sc, bi), 0.f));
        stf(&out[ob + CN],     fmaxf(fmaf(v.y, sc, bi), 0.f));
        stf(&out[ob + 2*CN],   fmaxf(fmaf(v.z, sc, bi), 0.f));
        stf(&out[ob + 3*CN],   fmaxf(fmaf(v.w, sc, bi), 0.f));
    }
}

extern "C" void kernel_launch(void* const* d_in, const int* in_sizes, int n_in,
                              void* d_out, int out_size, void* d_ws, size_t ws_size,
                              hipStream_t stream) {
    dim3 grid(BN * 16 * HN);   // 16384 blocks

    const long long nb    = (n_in > 0) ? (long long)in_sizes[0] : 0;
    const long long F32B  = (long long)BN * HN * WN * CN * 4;   // 134217728
    const long long BF16B = F32B / 2;                           //  67108864

    if (nb == F32B) {
        diffusion_kernel<float><<<grid, NTH, 0, stream>>>(
            (const float*)d_in[0], (const float*)d_in[1], (const float*)d_in[2],
            (const float*)d_in[3], (const float*)d_in[4], (const float*)d_in[5], (const float*)d_in[6],
            (const float*)d_in[7], (const float*)d_in[8], (const float*)d_in[9], (const float*)d_in[10],
            (const float*)d_in[11], (const float*)d_in[12], (const float*)d_in[13], (const float*)d_in[14],
            (float*)d_out, nullptr, 0);
    } else if (nb == BF16B) {
        diffusion_kernel<__hip_bfloat16><<<grid, NTH, 0, stream>>>(
            (const __hip_bfloat16*)d_in[0], (const __hip_bfloat16*)d_in[1], (const __hip_bfloat16*)d_in[2],
            (const __hip_bfloat16*)d_in[3], (const __hip_bfloat16*)d_in[4], (const __hip_bfloat16*)d_in[5], (const __hip_bfloat16*)d_in[6],
            (const __hip_bfloat16*)d_in[7], (const __hip_bfloat16*)d_in[8], (const __hip_bfloat16*)d_in[9], (const __hip_bfloat16*)d_in[10],
            (const __hip_bfloat16*)d_in[11], (const __hip_bfloat16*)d_in[12], (const __hip_bfloat16*)d_in[13], (const __hip_bfloat16*)d_in[14],
            (__hip_bfloat16*)d_out, nullptr, 0);
    } else if (ws_size >= 4) {
        int* flag = (int*)d_ws;
        probe_kernel<<<1, 256, 0, stream>>>((const unsigned int*)d_in[0], flag);

        diffusion_kernel<float><<<grid, NTH, 0, stream>>>(
            (const float*)d_in[0], (const float*)d_in[1], (const float*)d_in[2],
            (const float*)d_in[3], (const float*)d_in[4], (const float*)d_in[5], (const float*)d_in[6],
            (const float*)d_in[7], (const float*)d_in[8], (const float*)d_in[9], (const float*)d_in[10],
            (const float*)d_in[11], (const float*)d_in[12], (const float*)d_in[13], (const float*)d_in[14],
            (float*)d_out, flag, 0);

        diffusion_kernel<__hip_bfloat16><<<grid, NTH, 0, stream>>>(
            (const __hip_bfloat16*)d_in[0], (const __hip_bfloat16*)d_in[1], (const __hip_bfloat16*)d_in[2],
            (const __hip_bfloat16*)d_in[3], (const __hip_bfloat16*)d_in[4], (const __hip_bfloat16*)d_in[5], (const __hip_bfloat16*)d_in[6],
            (const __hip_bfloat16*)d_in[7], (const __hip_bfloat16*)d_in[8], (const __hip_bfloat16*)d_in[9], (const __hip_bfloat16*)d_in[10],
            (const __hip_bfloat16*)d_in[11], (const __hip_bfloat16*)d_in[12], (const __hip_bfloat16*)d_in[13], (const __hip_bfloat16*)d_in[14],
            (__hip_bfloat16*)d_out, flag, 1);
    } else {
        diffusion_kernel<float><<<grid, NTH, 0, stream>>>(
            (const float*)d_in[0], (const float*)d_in[1], (const float*)d_in[2],
            (const float*)d_in[3], (const float*)d_in[4], (const float*)d_in[5], (const float*)d_in[6],
            (const float*)d_in[7], (const float*)d_in[8], (const float*)d_in[9], (const float*)d_in[10],
            (const float*)d_in[11], (const float*)d_in[12], (const float*)d_in[13], (const float*)d_in[14],
            (float*)d_out, nullptr, 0);
    }
}